// Round 19
// baseline (397.503 us; speedup 1.0000x reference)
//
#include <hip/hip_runtime.h>
#include <hip/hip_bf16.h>
#include <math.h>

// ---------------- problem constants ----------------
constexpr int NA  = 3200;     // atoms
constexpr int NE  = 51200;    // edges
constexpr int C   = 128;      // channels
constexpr int NK  = 123;      // k-points with |k| <= 0.6
constexpr int NKP = 128;      // padded stride
constexpr int BG  = 8;        // graphs
constexpr int SFSPLIT = 8;    // k_sf split factor
constexpr float SKIPF = 0.57735026918962576f;  // 3^-0.5
constexpr float AVGN  = 16.0f;
constexpr size_t SFSZ = (size_t)BG * NK * C;   // one sf plane (125952)

__device__ __forceinline__ float dsilu(float x) { return x / (1.0f + expf(-x)); }

__device__ __forceinline__ unsigned short f2bf(float f) {
    unsigned int u = __float_as_uint(f);
    unsigned int r = (u + 0x7fffu + ((u >> 16) & 1u)) >> 16;
    return (unsigned short)r;
}
__device__ __forceinline__ float bf2f(unsigned short s) {
    return __uint_as_float(((unsigned int)s) << 16);
}

typedef __attribute__((ext_vector_type(8))) short short8;
typedef __attribute__((ext_vector_type(4))) float f32x4;

// ---------------- fused pre-MLP + Wup (3-stage bf16 MFMA, 32 rows/block) ----------------
__global__ __launch_bounds__(256, 2) void k_pre(
    const float* __restrict__ h,
    const unsigned short* __restrict__ W1t, const float* __restrict__ b1,
    const unsigned short* __restrict__ Wut,
    const unsigned short* __restrict__ W2t, const float* __restrict__ b2,
    float* __restrict__ hu, float* __restrict__ hres)
{
    constexpr int MT = 32, ASH = 136;
    __shared__ unsigned short Xs[MT * ASH];
    __shared__ unsigned short Ts[MT * ASH];
    __shared__ unsigned short Ws[128 * ASH];
    const int tid = threadIdx.x;
    const int m0 = blockIdx.x * MT;

    for (int idx = tid; idx < MT * 32; idx += 256) {
        int r = idx >> 5, c4 = idx & 31;
        float4 v = ((const float4*)h)[(size_t)(m0 + r) * 32 + c4];
        ushort4 pk;
        pk.x = f2bf(v.x); pk.y = f2bf(v.y); pk.z = f2bf(v.z); pk.w = f2bf(v.w);
        *(ushort4*)(Xs + r * ASH + c4 * 4) = pk;
    }
    for (int idx = tid; idx < 128 * 16; idx += 256) {
        int r = idx >> 4, s = idx & 15;
        *(short8*)(Ws + r * ASH + s * 8) = ((const short8*)W1t)[(size_t)r * 16 + s];
    }
    __syncthreads();

    const int wave = tid >> 6;
    const int lane = tid & 63;
    const int q = lane >> 4;
    const int l16 = lane & 15;
    const int mh = (wave & 1) * 16;
    const int nh = (wave >> 1) * 64;

    f32x4 acc[4];
#pragma unroll
    for (int ni = 0; ni < 4; ni++) acc[ni] = (f32x4){0.f, 0.f, 0.f, 0.f};
#pragma unroll
    for (int kc = 0; kc < 4; kc++) {
        short8 a = *(const short8*)(Xs + (mh + l16) * ASH + kc * 32 + q * 8);
#pragma unroll
        for (int ni = 0; ni < 4; ni++) {
            short8 b = *(const short8*)(Ws + (nh + ni * 16 + l16) * ASH + kc * 32 + q * 8);
            acc[ni] = __builtin_amdgcn_mfma_f32_16x16x32_bf16(a, b, acc[ni], 0, 0, 0);
        }
    }
#pragma unroll
    for (int ni = 0; ni < 4; ni++) {
        float bv = b1[nh + ni * 16 + l16];
#pragma unroll
        for (int r = 0; r < 4; r++)
            Ts[(mh + q * 4 + r) * ASH + nh + ni * 16 + l16] = f2bf(dsilu(acc[ni][r] + bv));
    }
    __syncthreads();
    for (int idx = tid; idx < 128 * 16; idx += 256) {
        int r = idx >> 4, s = idx & 15;
        *(short8*)(Ws + r * ASH + s * 8) = ((const short8*)Wut)[(size_t)r * 16 + s];
    }
    __syncthreads();
#pragma unroll
    for (int ni = 0; ni < 4; ni++) acc[ni] = (f32x4){0.f, 0.f, 0.f, 0.f};
#pragma unroll
    for (int kc = 0; kc < 4; kc++) {
        short8 a = *(const short8*)(Xs + (mh + l16) * ASH + kc * 32 + q * 8);
#pragma unroll
        for (int ni = 0; ni < 4; ni++) {
            short8 b = *(const short8*)(Ws + (nh + ni * 16 + l16) * ASH + kc * 32 + q * 8);
            acc[ni] = __builtin_amdgcn_mfma_f32_16x16x32_bf16(a, b, acc[ni], 0, 0, 0);
        }
    }
#pragma unroll
    for (int ni = 0; ni < 4; ni++) {
#pragma unroll
        for (int r = 0; r < 4; r++)
            hu[(size_t)(m0 + mh + q * 4 + r) * C + nh + ni * 16 + l16] = acc[ni][r];
    }
    __syncthreads();
    for (int idx = tid; idx < 128 * 16; idx += 256) {
        int r = idx >> 4, s = idx & 15;
        *(short8*)(Ws + r * ASH + s * 8) = ((const short8*)W2t)[(size_t)r * 16 + s];
    }
    __syncthreads();
#pragma unroll
    for (int ni = 0; ni < 4; ni++) acc[ni] = (f32x4){0.f, 0.f, 0.f, 0.f};
#pragma unroll
    for (int kc = 0; kc < 4; kc++) {
        short8 a = *(const short8*)(Ts + (mh + l16) * ASH + kc * 32 + q * 8);
#pragma unroll
        for (int ni = 0; ni < 4; ni++) {
            short8 b = *(const short8*)(Ws + (nh + ni * 16 + l16) * ASH + kc * 32 + q * 8);
            acc[ni] = __builtin_amdgcn_mfma_f32_16x16x32_bf16(a, b, acc[ni], 0, 0, 0);
        }
    }
#pragma unroll
    for (int ni = 0; ni < 4; ni++) {
        float bv = b2[nh + ni * 16 + l16];
#pragma unroll
        for (int r = 0; r < 4; r++) {
            int row = m0 + mh + q * 4 + r;
            int col = nh + ni * 16 + l16;
            hres[(size_t)row * C + col] = acc[ni][r] + bv + h[(size_t)row * C + col];
        }
    }
}

// ---------------- fused edge MLP: ef(8)->64->64->64->512, bf16 MFMA, 2-layer ----------------
// grid (2*NE/64, 8): blockIdx.y = W4 n-chunk. Stages 1-3 recomputed per chunk (cheap);
// no serial chunk loop -> 6 barriers/block, 12800 short blocks.
__global__ __launch_bounds__(256, 4) void k_edge_mlp(
    const float* __restrict__ efb,
    const unsigned short* __restrict__ W1bt, const float* __restrict__ rb1,
    const unsigned short* __restrict__ W2bt, const float* __restrict__ rb2,
    const unsigned short* __restrict__ W3bt, const float* __restrict__ rb3,
    const unsigned short* __restrict__ W4bt,
    unsigned short* __restrict__ wbuf)
{
    constexpr int MT = 64;
    constexpr int TS = 72;    // T1/T2/WB row stride (shorts)
    constexpr int AS0 = 40;   // A0 row stride (shorts), K=32 padded
    __shared__ __align__(16) char smem[32768];
    unsigned short* A0 = (unsigned short*)smem;            // 64*40*2 = 5120
    unsigned short* T1 = (unsigned short*)(smem + 5120);   // 64*72*2 = 9216
    unsigned short* T2 = (unsigned short*)(smem + 14336);  // 9216
    unsigned short* WB = (unsigned short*)(smem + 23552);  // 9216
    const int tid = threadIdx.x;
    const int nb = NE / MT;
    const int layer = (blockIdx.x >= nb) ? 1 : 0;
    const size_t m0 = (size_t)(blockIdx.x - layer * nb) * MT;
    const int nt = blockIdx.y;

    // stage ef (f32 [slot][8]) -> A0 bf16, zero-pad k in [8,32)
    if (tid < 128) {
        int r = tid >> 1, hf = tid & 1;
        float4 v = ((const float4*)efb)[(m0 + r) * 2 + hf];
        ushort4 pk;
        pk.x = f2bf(v.x); pk.y = f2bf(v.y); pk.z = f2bf(v.z); pk.w = f2bf(v.w);
        *(ushort4*)(A0 + r * AS0 + hf * 4) = pk;
    }
    const short8 z8 = (short8){0,0,0,0,0,0,0,0};
    if (tid < 192) {
        int r = tid / 3, s = tid - r * 3;
        *(short8*)(A0 + r * AS0 + 8 + s * 8) = z8;
    }
    // load W1 ([64][32])
    {
        int r = tid >> 2, s = tid & 3;
        *(short8*)(WB + r * TS + s * 8) =
            ((const short8*)(W1bt + (size_t)layer * 64 * 32))[r * 4 + s];
    }
    __syncthreads();

    const int wave = tid >> 6;
    const int lane = tid & 63;
    const int q = lane >> 4;
    const int l16 = lane & 15;
    const int mw = wave * 16;   // 4 waves x 16 rows = 64 rows

    const float* b1 = rb1 + layer * 64;
    const float* b2 = rb2 + layer * 64;
    const float* b3 = rb3 + layer * 64;

    f32x4 acc[4];
    // ---- stage 1: K=32 ----
#pragma unroll
    for (int ni = 0; ni < 4; ni++) acc[ni] = (f32x4){0.f, 0.f, 0.f, 0.f};
    {
        short8 a = *(const short8*)(A0 + (mw + l16) * AS0 + q * 8);
#pragma unroll
        for (int ni = 0; ni < 4; ni++) {
            short8 b = *(const short8*)(WB + (ni * 16 + l16) * TS + q * 8);
            acc[ni] = __builtin_amdgcn_mfma_f32_16x16x32_bf16(a, b, acc[ni], 0, 0, 0);
        }
    }
#pragma unroll
    for (int ni = 0; ni < 4; ni++) {
        float bv = b1[ni * 16 + l16];
#pragma unroll
        for (int r = 0; r < 4; r++)
            T1[(mw + q * 4 + r) * TS + ni * 16 + l16] = f2bf(dsilu(acc[ni][r] + bv));
    }
    __syncthreads();
    // ---- stage 2: W2, K=64, T1 -> T2 ----
    for (int idx = tid; idx < 512; idx += 256) {
        int r = idx >> 3, s = idx & 7;
        *(short8*)(WB + r * TS + s * 8) =
            ((const short8*)(W2bt + (size_t)layer * 64 * 64))[r * 8 + s];
    }
    __syncthreads();
#pragma unroll
    for (int ni = 0; ni < 4; ni++) acc[ni] = (f32x4){0.f, 0.f, 0.f, 0.f};
#pragma unroll
    for (int kc = 0; kc < 2; kc++) {
        short8 a = *(const short8*)(T1 + (mw + l16) * TS + kc * 32 + q * 8);
#pragma unroll
        for (int ni = 0; ni < 4; ni++) {
            short8 b = *(const short8*)(WB + (ni * 16 + l16) * TS + kc * 32 + q * 8);
            acc[ni] = __builtin_amdgcn_mfma_f32_16x16x32_bf16(a, b, acc[ni], 0, 0, 0);
        }
    }
#pragma unroll
    for (int ni = 0; ni < 4; ni++) {
        float bv = b2[ni * 16 + l16];
#pragma unroll
        for (int r = 0; r < 4; r++)
            T2[(mw + q * 4 + r) * TS + ni * 16 + l16] = f2bf(dsilu(acc[ni][r] + bv));
    }
    __syncthreads();
    // ---- stage 3: W3, K=64, T2 -> T1 ----
    for (int idx = tid; idx < 512; idx += 256) {
        int r = idx >> 3, s = idx & 7;
        *(short8*)(WB + r * TS + s * 8) =
            ((const short8*)(W3bt + (size_t)layer * 64 * 64))[r * 8 + s];
    }
    __syncthreads();
#pragma unroll
    for (int ni = 0; ni < 4; ni++) acc[ni] = (f32x4){0.f, 0.f, 0.f, 0.f};
#pragma unroll
    for (int kc = 0; kc < 2; kc++) {
        short8 a = *(const short8*)(T2 + (mw + l16) * TS + kc * 32 + q * 8);
#pragma unroll
        for (int ni = 0; ni < 4; ni++) {
            short8 b = *(const short8*)(WB + (ni * 16 + l16) * TS + kc * 32 + q * 8);
            acc[ni] = __builtin_amdgcn_mfma_f32_16x16x32_bf16(a, b, acc[ni], 0, 0, 0);
        }
    }
#pragma unroll
    for (int ni = 0; ni < 4; ni++) {
        float bv = b3[ni * 16 + l16];
#pragma unroll
        for (int r = 0; r < 4; r++)
            T1[(mw + q * 4 + r) * TS + ni * 16 + l16] = f2bf(dsilu(acc[ni][r] + bv));
    }
    __syncthreads();

    // ---- stage 4: single W4 chunk nt ----
    const unsigned short* W4l = W4bt + (size_t)layer * 512 * 64;
    unsigned short* wout = wbuf + ((size_t)layer * NE + m0) * 512;
    for (int idx = tid; idx < 512; idx += 256) {
        int r = idx >> 3, s = idx & 7;
        *(short8*)(WB + r * TS + s * 8) = ((const short8*)W4l)[(nt * 64 + r) * 8 + s];
    }
    __syncthreads();
#pragma unroll
    for (int ni = 0; ni < 4; ni++) acc[ni] = (f32x4){0.f, 0.f, 0.f, 0.f};
#pragma unroll
    for (int kc = 0; kc < 2; kc++) {
        short8 a = *(const short8*)(T1 + (mw + l16) * TS + kc * 32 + q * 8);
#pragma unroll
        for (int ni = 0; ni < 4; ni++) {
            short8 b = *(const short8*)(WB + (ni * 16 + l16) * TS + kc * 32 + q * 8);
            acc[ni] = __builtin_amdgcn_mfma_f32_16x16x32_bf16(a, b, acc[ni], 0, 0, 0);
        }
    }
#pragma unroll
    for (int ni = 0; ni < 4; ni++)
#pragma unroll
        for (int r = 0; r < 4; r++) {
            int row = mw + q * 4 + r;
            int col = nt * 64 + ni * 16 + l16;
            wout[(size_t)row * 512 + col] = f2bf(acc[ni][r]);
        }
}

// ---------------- setup megakernel ----------------
constexpr int TK0 = NA;
constexpr int TK1 = TK0 + 8;
constexpr int TK2 = TK1 + 512;
constexpr int TK3 = TK2 + 64;
constexpr int TK4 = TK3 + 64;
constexpr int TK4b = TK4 + 32;     // W1 padded bf16
constexpr int TK5 = TK4b + 256;
constexpr int TK6 = TK5 + 256;
constexpr int TK7 = TK6 + 256;
constexpr int TK8 = TK7 + 256;
constexpr int TK9 = TK8 + 256;
constexpr int TKEND = TK9 + 1;

__device__ __forceinline__ float sincn(float x) {
    float px = 3.14159265358979323846f * x;
    return (fabsf(px) < 1e-8f) ? 1.0f : (sinf(px) / px);
}

__device__ __forceinline__ void convT128_task(
    const float* __restrict__ W, unsigned short* __restrict__ Wt, int idx)
{
    int layer = idx >> 14, rem = idx & 16383;
    int n = rem >> 7, k = rem & 127;
    Wt[((size_t)layer << 14) + (n << 7) + k] = f2bf(W[((size_t)layer << 14) + (k << 7) + n]);
}

__global__ __launch_bounds__(128) void k_setup(
    const float* __restrict__ na, const float* __restrict__ Wemb,
    const float* __restrict__ aE, const int* __restrict__ batch,
    const float* __restrict__ pos, const float* __restrict__ kgrid,
    const float* __restrict__ krbf, const float* __restrict__ Wdown,
    const float* __restrict__ rW4, const float* __restrict__ rW2,
    const float* __restrict__ rW3, const float* __restrict__ rW1,
    const float* __restrict__ Wm1, const float* __restrict__ Wm2,
    const float* __restrict__ Wpre1, const float* __restrict__ Wpre2,
    const float* __restrict__ Wup,
    float* __restrict__ h, float* __restrict__ e0buf,
    float* __restrict__ cosd, float* __restrict__ sind,
    unsigned short* __restrict__ cosdb, unsigned short* __restrict__ sindb,
    float* __restrict__ kdwn,
    unsigned short* __restrict__ W4bt, unsigned short* __restrict__ W2bt,
    unsigned short* __restrict__ W3bt, unsigned short* __restrict__ W1bt,
    unsigned short* __restrict__ Wm1bt, unsigned short* __restrict__ Wm2bt,
    unsigned short* __restrict__ Wpre1bt, unsigned short* __restrict__ Wpre2bt,
    unsigned short* __restrict__ Wupbt,
    int* __restrict__ gs)
{
    const int bx = blockIdx.x;
    const int t = threadIdx.x;
    __shared__ int cnt[BG];

    if (bx < TK0) {
        int n = bx, c = t;
        float s = 0.f;
#pragma unroll
        for (int k = 0; k < 10; k++) s += na[n * 10 + k] * Wemb[k * C + c];
        h[(size_t)n * C + c] = s;
        if (c == 0) {
            float e = 0.f;
#pragma unroll
            for (int k = 0; k < 10; k++) e += na[n * 10 + k] * aE[k];
            e0buf[n] = e;
        }
        float p0 = pos[n * 3 + 0], p1 = pos[n * 3 + 1], p2 = pos[n * 3 + 2];
        float sd = sincn(0.1f * p0) * sincn(0.1f * p1) * sincn(0.1f * p2);
        int k = t;
        float cv = 0.f, sv = 0.f;
        if (k < NK) {
            float d = p0 * kgrid[k * 3 + 0] + p1 * kgrid[k * 3 + 1] + p2 * kgrid[k * 3 + 2];
            float sn, cs;
            sincosf(d, &sn, &cs);
            cv = sd * cs;
            sv = sd * sn;
        }
        cosd[(size_t)n * NKP + k] = cv;
        sind[(size_t)n * NKP + k] = sv;
        cosdb[(size_t)n * NKP + k] = f2bf(cv);
        sindb[(size_t)n * NKP + k] = f2bf(sv);
    } else if (bx < TK1) {
        int slot = (bx - TK0) * 128 + t;
        if (slot < NK * 8) {
            int k = slot >> 3, j = slot & 7;
            float s = 0.f;
            for (int r = 0; r < 128; r++) s += krbf[k * 128 + r] * Wdown[r * 8 + j];
            kdwn[slot] = s;
        }
    } else if (bx < TK2) {
        int idx = (bx - TK1) * 128 + t;
        int layer = idx >> 15, rem = idx & 32767;
        int n = rem >> 6, k = rem & 63;
        W4bt[((size_t)layer * 512 + n) * 64 + k] = f2bf(rW4[((size_t)layer * 64 + k) * 512 + n]);
    } else if (bx < TK3) {
        int idx = (bx - TK2) * 128 + t;
        int layer = idx >> 12, rem = idx & 4095;
        int n = rem >> 6, k = rem & 63;
        W2bt[((size_t)layer * 64 + n) * 64 + k] = f2bf(rW2[((size_t)layer * 64 + k) * 64 + n]);
    } else if (bx < TK4) {
        int idx = (bx - TK3) * 128 + t;
        int layer = idx >> 12, rem = idx & 4095;
        int n = rem >> 6, k = rem & 63;
        W3bt[((size_t)layer * 64 + n) * 64 + k] = f2bf(rW3[((size_t)layer * 64 + k) * 64 + n]);
    } else if (bx < TK4b) {
        int idx = (bx - TK4) * 128 + t;   // over 2*64*32
        int layer = idx >> 11, rem = idx & 2047;
        int n = rem >> 5, k = rem & 31;
        W1bt[((size_t)layer * 64 + n) * 32 + k] =
            (k < 8) ? f2bf(rW1[((size_t)layer * 8 + k) * 64 + n]) : (unsigned short)0;
    } else if (bx < TK5) {
        convT128_task(Wm1, Wm1bt, (bx - TK4b) * 128 + t);
    } else if (bx < TK6) {
        convT128_task(Wm2, Wm2bt, (bx - TK5) * 128 + t);
    } else if (bx < TK7) {
        convT128_task(Wpre1, Wpre1bt, (bx - TK6) * 128 + t);
    } else if (bx < TK8) {
        convT128_task(Wpre2, Wpre2bt, (bx - TK7) * 128 + t);
    } else if (bx < TK9) {
        convT128_task(Wup, Wupbt, (bx - TK8) * 128 + t);
    } else {
        if (t < BG) cnt[t] = 0;
        __syncthreads();
        for (int n = t; n < NA; n += 128) atomicAdd(&cnt[batch[n]], 1);
        __syncthreads();
        if (t == 0) {
            int s = 0;
            for (int b = 0; b < BG; b++) { gs[b] = s; s += cnt[b]; }
            gs[BG] = s;
        }
    }
}

// ---------------- degree count ----------------
__global__ __launch_bounds__(256) void k_count(const int* __restrict__ eidx, int* __restrict__ deg)
{
    int e = blockIdx.x * 256 + threadIdx.x;
    if (e < NE) atomicAdd(&deg[eidx[NE + e]], 1);
}

// ---------------- CSR by dst ----------------
__global__ __launch_bounds__(1024) void k_scan(
    const int* __restrict__ deg, int* __restrict__ offs, int* __restrict__ cursor)
{
    __shared__ int sc[1024];
    int tid = threadIdx.x;
    int base = tid * 4;
    int v[4]; int s = 0;
#pragma unroll
    for (int i = 0; i < 4; i++) {
        int idx = base + i;
        int d = (idx < NA) ? deg[idx] : 0;
        v[i] = s; s += d;
    }
    sc[tid] = s;
    __syncthreads();
    for (int ofs = 1; ofs < 1024; ofs <<= 1) {
        int t = (tid >= ofs) ? sc[tid - ofs] : 0;
        __syncthreads();
        sc[tid] += t;
        __syncthreads();
    }
    int excl = (tid > 0) ? sc[tid - 1] : 0;
#pragma unroll
    for (int i = 0; i < 4; i++) {
        int idx = base + i;
        if (idx < NA) { int o = excl + v[i]; offs[idx] = o; cursor[idx] = o; }
    }
    if (tid == 1023) offs[NA] = sc[1023];
}

// fill: perm[p] = e, srcP[p] = src(e)
__global__ __launch_bounds__(256) void k_fill(
    const int* __restrict__ eidx, int* __restrict__ cursor,
    int* __restrict__ perm, int* __restrict__ srcP)
{
    int e = blockIdx.x * 256 + threadIdx.x;
    if (e < NE) {
        int d = eidx[NE + e];
        int p = atomicAdd(&cursor[d], 1);
        perm[p] = e;
        srcP[p] = eidx[e];
    }
}

// ---------------- edge geometry (slot-ordered via perm) ----------------
__global__ __launch_bounds__(256) void k_edge_geom(
    const float* __restrict__ pos, const float* __restrict__ shifts,
    const int* __restrict__ eidx, const int* __restrict__ perm,
    float* __restrict__ Y, float* __restrict__ ef)
{
    int j = blockIdx.x * 256 + threadIdx.x;
    if (j >= NE) return;
    int e = perm[j];
    int s = eidx[e], d = eidx[NE + e];
    float vx = pos[d * 3 + 0] - pos[s * 3 + 0] + shifts[e * 3 + 0];
    float vy = pos[d * 3 + 1] - pos[s * 3 + 1] + shifts[e * 3 + 1];
    float vz = pos[d * 3 + 2] - pos[s * 3 + 2] + shifts[e * 3 + 2];
    float r = sqrtf(vx * vx + vy * vy + vz * vz);
    float rinv = 1.0f / fmaxf(r, 1e-9f);
    float x = vx * rinv, y = vy * rinv, z = vz * rinv;

    const float s3 = 1.7320508075688772f, s5 = 2.2360679774997896f, s15 = 3.8729833462074170f;
    const float c70 = 2.0916500663351889f;
    const float c105 = 10.246950765959598f;
    const float c42 = 1.6201851746019651f;
    const float c7 = 1.3228756555322954f;
    float o[16];
    o[0] = 1.0f;
    o[1] = s3 * x; o[2] = s3 * y; o[3] = s3 * z;
    o[4] = s15 * x * y; o[5] = s15 * y * z; o[6] = 0.5f * s5 * (3.f * z * z - 1.f);
    o[7] = s15 * x * z; o[8] = 0.5f * s15 * (x * x - y * y);
    o[9]  = c70 * y * (3.f * x * x - y * y);
    o[10] = c105 * x * y * z;
    o[11] = c42 * y * (5.f * z * z - 1.f);
    o[12] = c7 * z * (5.f * z * z - 3.f);
    o[13] = c42 * x * (5.f * z * z - 1.f);
    o[14] = 0.5f * c105 * z * (x * x - y * y);
    o[15] = c70 * x * (x * x - 3.f * y * y);
    float4* Y4 = (float4*)(Y + (size_t)j * 16);
    Y4[0] = make_float4(o[0], o[1], o[2], o[3]);
    Y4[1] = make_float4(o[4], o[5], o[6], o[7]);
    Y4[2] = make_float4(o[8], o[9], o[10], o[11]);
    Y4[3] = make_float4(o[12], o[13], o[14], o[15]);

    float uu = fminf(fmaxf(r * 0.2f, 0.f), 1.f);
    float u2 = uu * uu, u4 = u2 * u2, u5 = u4 * uu, u6 = u5 * uu, u7 = u6 * uu;
    float env = 1.f - 21.f * u5 + 35.f * u6 - 15.f * u7;
    env = (r < 5.0f) ? env : 0.0f;
    float pref = 0.63245553203367587f * rinv * env;
    const float pio5 = 0.62831853071795865f;
    float efv[8];
#pragma unroll
    for (int n1 = 1; n1 <= 8; n1++) efv[n1 - 1] = pref * sinf(n1 * pio5 * r);
    float4* E4 = (float4*)(ef + (size_t)j * 8);
    E4[0] = make_float4(efv[0], efv[1], efv[2], efv[3]);
    E4[1] = make_float4(efv[4], efv[5], efv[6], efv[7]);
}

// ---------------- Ewald: structure-factor partials (kfilter fused inline) ----------------
__global__ __launch_bounds__(256, 4) void k_sf(
    const float* __restrict__ hres, const float* __restrict__ cosd, const float* __restrict__ sind,
    const int* __restrict__ gs, const float* __restrict__ kdwn, const float* __restrict__ WupE,
    float* __restrict__ sfp)
{
    const int b = blockIdx.x, kt = blockIdx.y, sp = blockIdx.z;
    const int n0 = gs[b], n1 = gs[b + 1];
    const int cnt = n1 - n0;
    const int per = (cnt + SFSPLIT - 1) / SFSPLIT;
    const int cs = n0 + sp * per;
    const int ce = min(cs + per, n1);

    __shared__ float Hs[32 * 128];
    __shared__ float Cs[32 * 32];
    __shared__ float Ss[32 * 32];

    const int tid = threadIdx.x;
    const int tx = tid & 31;
    const int ty = tid >> 5;

    float accR[4][4], accI[4][4];
#pragma unroll
    for (int i = 0; i < 4; i++)
#pragma unroll
        for (int j = 0; j < 4; j++) { accR[i][j] = 0.f; accI[i][j] = 0.f; }

    float4* H4 = (float4*)Hs;
    float4* C4 = (float4*)Cs;
    float4* S4 = (float4*)Ss;

    for (int nb = cs; nb < ce; nb += 32) {
        __syncthreads();
        for (int idx = tid; idx < 32 * 32; idx += 256) {
            int r = idx >> 5, c4 = idx & 31;
            int n = nb + r;
            H4[idx] = (n < ce) ? ((const float4*)hres)[(size_t)n * 32 + c4]
                               : make_float4(0.f, 0.f, 0.f, 0.f);
        }
        for (int idx = tid; idx < 32 * 8; idx += 256) {
            int r = idx >> 3, k4 = idx & 7;
            int n = nb + r;
            float4 cv = make_float4(0.f, 0.f, 0.f, 0.f), sv = cv;
            if (n < ce) {
                cv = ((const float4*)cosd)[(size_t)n * 32 + kt * 8 + k4];
                sv = ((const float4*)sind)[(size_t)n * 32 + kt * 8 + k4];
            }
            C4[idx] = cv;
            S4[idx] = sv;
        }
        __syncthreads();
        const int lim = min(32, ce - nb);
        for (int n = 0; n < lim; n++) {
            float4 hv = H4[n * 32 + tx];
            float4 cv = C4[n * 8 + ty];
            float4 sv = S4[n * 8 + ty];
            float h[4] = { hv.x, hv.y, hv.z, hv.w };
            float ck[4] = { cv.x, cv.y, cv.z, cv.w };
            float sk[4] = { sv.x, sv.y, sv.z, sv.w };
#pragma unroll
            for (int i = 0; i < 4; i++)
#pragma unroll
                for (int j = 0; j < 4; j++) {
                    accR[i][j] += ck[i] * h[j];
                    accI[i][j] += sk[i] * h[j];
                }
        }
    }

    const int kbase = kt * 32 + ty * 4;
    float* baseR = sfp + (size_t)sp * SFSZ;
    float* baseI = sfp + (size_t)(SFSPLIT + sp) * SFSZ;
#pragma unroll
    for (int i = 0; i < 4; i++) {
        int k = kbase + i;
        if (k < NK) {
            float4 kfv = make_float4(0.f, 0.f, 0.f, 0.f);
#pragma unroll
            for (int j = 0; j < 8; j++) {
                float kd = kdwn[k * 8 + j];
                float4 wv = ((const float4*)WupE)[(size_t)j * 32 + tx];
                kfv.x += kd * wv.x; kfv.y += kd * wv.y;
                kfv.z += kd * wv.z; kfv.w += kd * wv.w;
            }
            float vx = kfv.x * 0.01f, vy = kfv.y * 0.01f, vz = kfv.z * 0.01f, vw = kfv.w * 0.01f;
            size_t o = ((size_t)(b * NK + k)) * C + tx * 4;
            *(float4*)(baseR + o) = make_float4(accR[i][0] * vx, accR[i][1] * vy,
                                                accR[i][2] * vz, accR[i][3] * vw);
            *(float4*)(baseI + o) = make_float4(accI[i][0] * vx, accI[i][1] * vy,
                                                accI[i][2] * vz, accI[i][3] * vw);
        }
    }
}

// ---------------- reduce sfp partials -> bf16 transposed sfrT/sfiT [b][c][kpad] ----------------
__global__ __launch_bounds__(256) void k_sfredT(
    const float* __restrict__ sfp,
    unsigned short* __restrict__ sfrT, unsigned short* __restrict__ sfiT)
{
    const int kc = blockIdx.x * 16;
    const int b = blockIdx.y;
    __shared__ float Tr[16 * 128];
    __shared__ float Ti[16 * 128];
    const int tid = threadIdx.x;
    const size_t S4 = SFSZ / 4;
    const float4* P4 = (const float4*)sfp;

    for (int idx = tid; idx < 16 * 32; idx += 256) {
        int kk = idx >> 5, c4 = idx & 31;
        float4 ar = make_float4(0.f, 0.f, 0.f, 0.f), ai = ar;
        if (kc + kk < NK) {
            size_t off = ((size_t)(b * NK + kc + kk)) * 32 + c4;
#pragma unroll
            for (int sp = 0; sp < SFSPLIT; sp++) {
                float4 r = P4[(size_t)sp * S4 + off];
                ar.x += r.x; ar.y += r.y; ar.z += r.z; ar.w += r.w;
                float4 q = P4[(size_t)(SFSPLIT + sp) * S4 + off];
                ai.x += q.x; ai.y += q.y; ai.z += q.z; ai.w += q.w;
            }
        }
        ((float4*)Tr)[idx] = ar;
        ((float4*)Ti)[idx] = ai;
    }
    __syncthreads();
    const int c = tid & 127;
    const int sel = tid >> 7;
    const float* T = sel ? Ti : Tr;
    unsigned short* out = sel ? sfiT : sfrT;
    unsigned short tmp[16];
#pragma unroll
    for (int kk = 0; kk < 16; kk++) tmp[kk] = f2bf(T[kk * 128 + c]);
    short8* dst = (short8*)(out + ((size_t)(b * 128 + c)) * NKP + kc);
    dst[0] = *(short8*)(tmp);
    dst[1] = *(short8*)(tmp + 8);
}

// ---------------- fused he back-projection (MFMA) + he-MLP ----------------
__global__ __launch_bounds__(256) void k_he_mlp(
    const unsigned short* __restrict__ cosdb, const unsigned short* __restrict__ sindb,
    const unsigned short* __restrict__ sfrT, const unsigned short* __restrict__ sfiT,
    const int* __restrict__ gs,
    const unsigned short* __restrict__ Wm1t, const float* __restrict__ bm1,
    const unsigned short* __restrict__ Wm2t, const float* __restrict__ bm2,
    float* __restrict__ he2)
{
    constexpr int ASH = 136;
    constexpr int BSH = 72;
    __shared__ __align__(16) char smem[54272];
    unsigned short* Ca = (unsigned short*)smem;
    unsigned short* Sa = (unsigned short*)(smem + 8704);
    unsigned short* Br = (unsigned short*)(smem + 17408);
    unsigned short* Bi = (unsigned short*)(smem + 35840);
    unsigned short* Xs = (unsigned short*)smem;
    unsigned short* Ts = (unsigned short*)(smem + 8704);
    unsigned short* Ws = (unsigned short*)(smem + 17408);

    const int b = blockIdx.y;
    const int a0g = gs[b], a1g = gs[b + 1];
    const int a0 = a0g + blockIdx.x * 32;
    if (a0 >= a1g) return;
    const int nal = min(32, a1g - a0);
    const int tid = threadIdx.x;

    const short8 z8 = (short8){0,0,0,0,0,0,0,0};
    for (int idx = tid; idx < 32 * 16; idx += 256) {
        int r = idx >> 4, s = idx & 15;
        short8 cv = z8, sv = z8;
        if (r < nal) {
            cv = ((const short8*)cosdb)[(size_t)(a0 + r) * 16 + s];
            sv = ((const short8*)sindb)[(size_t)(a0 + r) * 16 + s];
        }
        *(short8*)(Ca + r * ASH + s * 8) = cv;
        *(short8*)(Sa + r * ASH + s * 8) = sv;
    }

    const int wave = tid >> 6;
    const int lane = tid & 63;
    const int q = lane >> 4;
    const int l16 = lane & 15;
    const int mh = (wave & 1) * 16;
    const int nh = (wave >> 1) * 64;

    f32x4 acc[4];
#pragma unroll
    for (int ni = 0; ni < 4; ni++) acc[ni] = (f32x4){0.f, 0.f, 0.f, 0.f};

#pragma unroll
    for (int kc2 = 0; kc2 < 2; kc2++) {
        __syncthreads();
        for (int idx = tid; idx < 128 * 8; idx += 256) {
            int c = idx >> 3, s = idx & 7;
            size_t gi = (size_t)(b * 128 + c) * 16 + kc2 * 8 + s;
            *(short8*)(Br + c * BSH + s * 8) = ((const short8*)sfrT)[gi];
            *(short8*)(Bi + c * BSH + s * 8) = ((const short8*)sfiT)[gi];
        }
        __syncthreads();
#pragma unroll
        for (int ks = 0; ks < 2; ks++) {
            short8 ar = *(const short8*)(Ca + (mh + l16) * ASH + kc2 * 64 + ks * 32 + q * 8);
            short8 ai = *(const short8*)(Sa + (mh + l16) * ASH + kc2 * 64 + ks * 32 + q * 8);
#pragma unroll
            for (int ni = 0; ni < 4; ni++) {
                short8 br = *(const short8*)(Br + (nh + ni * 16 + l16) * BSH + ks * 32 + q * 8);
                acc[ni] = __builtin_amdgcn_mfma_f32_16x16x32_bf16(ar, br, acc[ni], 0, 0, 0);
                short8 bi = *(const short8*)(Bi + (nh + ni * 16 + l16) * BSH + ks * 32 + q * 8);
                acc[ni] = __builtin_amdgcn_mfma_f32_16x16x32_bf16(ai, bi, acc[ni], 0, 0, 0);
            }
        }
    }
    __syncthreads();

#pragma unroll
    for (int ni = 0; ni < 4; ni++) {
#pragma unroll
        for (int r = 0; r < 4; r++)
            Xs[(mh + q * 4 + r) * ASH + nh + ni * 16 + l16] = f2bf(acc[ni][r]);
    }
    __syncthreads();
    for (int idx = tid; idx < 128 * 16; idx += 256) {
        int r = idx >> 4, s = idx & 15;
        *(short8*)(Ws + r * ASH + s * 8) = ((const short8*)Wm1t)[(size_t)r * 16 + s];
    }
    __syncthreads();

    f32x4 acc2[4];
#pragma unroll
    for (int ni = 0; ni < 4; ni++) acc2[ni] = (f32x4){0.f, 0.f, 0.f, 0.f};
#pragma unroll
    for (int kc = 0; kc < 4; kc++) {
        short8 a = *(const short8*)(Xs + (mh + l16) * ASH + kc * 32 + q * 8);
#pragma unroll
        for (int ni = 0; ni < 4; ni++) {
            short8 bb = *(const short8*)(Ws + (nh + ni * 16 + l16) * ASH + kc * 32 + q * 8);
            acc2[ni] = __builtin_amdgcn_mfma_f32_16x16x32_bf16(a, bb, acc2[ni], 0, 0, 0);
        }
    }
#pragma unroll
    for (int ni = 0; ni < 4; ni++) {
        float bv = bm1[nh + ni * 16 + l16];
#pragma unroll
        for (int r = 0; r < 4; r++)
            Ts[(mh + q * 4 + r) * ASH + nh + ni * 16 + l16] = f2bf(dsilu(acc2[ni][r] + bv));
    }
    __syncthreads();
    for (int idx = tid; idx < 128 * 16; idx += 256) {
        int r = idx >> 4, s = idx & 15;
        *(short8*)(Ws + r * ASH + s * 8) = ((const short8*)Wm2t)[(size_t)r * 16 + s];
    }
    __syncthreads();
#pragma unroll
    for (int ni = 0; ni < 4; ni++) acc2[ni] = (f32x4){0.f, 0.f, 0.f, 0.f};
#pragma unroll
    for (int kc = 0; kc < 4; kc++) {
        short8 a = *(const short8*)(Ts + (mh + l16) * ASH + kc * 32 + q * 8);
#pragma unroll
        for (int ni = 0; ni < 4; ni++) {
            short8 bb = *(const short8*)(Ws + (nh + ni * 16 + l16) * ASH + kc * 32 + q * 8);
            acc2[ni] = __builtin_amdgcn_mfma_f32_16x16x32_bf16(a, bb, acc2[ni], 0, 0, 0);
        }
    }
#pragma unroll
    for (int ni = 0; ni < 4; ni++) {
        int col = nh + ni * 16 + l16;
        float bv = bm2[col];
#pragma unroll
        for (int r = 0; r < 4; r++) {
            int lrow = mh + q * 4 + r;
            if (lrow < nal)
                he2[(size_t)(a0 + lrow) * C + col] = dsilu(acc2[ni][r] + bv);
        }
    }
}

// ---------------- fused gather (slot-ordered) + Wmix + residual + energy ----------------
__global__ __launch_bounds__(128) void k_gather_mix(
    const unsigned short* __restrict__ wbuf, const float* __restrict__ hu,
    const float* __restrict__ Y, const int* __restrict__ srcP,
    const int* __restrict__ offs,
    const float* __restrict__ w2, const float* __restrict__ w3,
    const float* __restrict__ Wmix, const float* __restrict__ h,
    const float* __restrict__ he2,
    const float* __restrict__ Wr0, const float* __restrict__ Wr1a,
    const float* __restrict__ Wr1b, int mode,
    float* __restrict__ hn, float* __restrict__ nebuf)
{
    int n = blockIdx.x, c = threadIdx.x;
    int j0 = offs[n], j1 = offs[n + 1];
    float A[16];
#pragma unroll
    for (int s = 0; s < 16; s++) A[s] = 0.f;
    for (int j = j0; j < j1; j++) {
        int s = srcP[j];
        float huc = hu[(size_t)s * C + c];
        ushort4 wv = *(const ushort4*)(wbuf + (size_t)j * 512 + c * 4);
        const float4* Yp = (const float4*)(Y + (size_t)j * 16);
        float4 y0 = Yp[0], y1 = Yp[1], y2 = Yp[2], y3 = Yp[3];
        float m0 = bf2f(wv.x) * huc, m1 = bf2f(wv.y) * huc;
        float m2 = bf2f(wv.z) * huc, m3 = bf2f(wv.w) * huc;
        A[0] += m0 * y0.x;
        A[1] += m1 * y0.y;  A[2]  += m1 * y0.z;  A[3]  += m1 * y0.w;
        A[4] += m2 * y1.x;  A[5]  += m2 * y1.y;  A[6]  += m2 * y1.z;  A[7] += m2 * y1.w;
        A[8] += m2 * y2.x;
        A[9] += m3 * y2.y;  A[10] += m3 * y2.z;  A[11] += m3 * y2.w;
        A[12] += m3 * y3.x; A[13] += m3 * y3.y;  A[14] += m3 * y3.z;  A[15] += m3 * y3.w;
    }
    const float inv = 1.0f / AVGN;
#pragma unroll
    for (int s = 0; s < 16; s++) A[s] *= inv;
    float scal = A[0];
    float i0 = A[0] * A[0];
    float i1 = A[1] * A[1] + A[2] * A[2] + A[3] * A[3];
    float i2 = A[4] * A[4] + A[5] * A[5] + A[6] * A[6] + A[7] * A[7] + A[8] * A[8];
    float i3 = A[9] * A[9] + A[10] * A[10] + A[11] * A[11] + A[12] * A[12] +
               A[13] * A[13] + A[14] * A[14] + A[15] * A[15];
    float t2 = i0 * w2[c] + i1 * w2[C + c] + i2 * w2[2 * C + c] + i3 * w2[3 * C + c];
    float t3 = i0 * w3[c] + i1 * w3[C + c] + i2 * w3[2 * C + c] + i3 * w3[3 * C + c];
    float fe_c = scal + t2 + scal * t3;

    __shared__ float fs[128];
    __shared__ float red[16];
    fs[c] = fe_c;
    __syncthreads();

    float mix = 0.f;
#pragma unroll 8
    for (int k = 0; k < 128; k++) mix += fs[k] * Wmix[(size_t)k * C + c];

    float hnv = SKIPF * (mix + h[(size_t)n * C + c] + he2[(size_t)n * C + c]);
    hn[(size_t)n * C + c] = hnv;

    __syncthreads();
    fs[c] = hnv;
    __syncthreads();

    if (mode == 0) {
        float v = hnv * Wr0[c];
#pragma unroll
        for (int o = 32; o; o >>= 1) v += __shfl_down(v, o, 64);
        if ((c & 63) == 0) red[c >> 6] = v;
        __syncthreads();
        if (c == 0) nebuf[n] = red[0] + red[1];
    } else {
        if (c < 16) {
            float s = 0.f;
#pragma unroll 8
            for (int cc = 0; cc < 128; cc++) s += fs[cc] * Wr1a[cc * 16 + c];
            red[c] = dsilu(s) * Wr1b[c];
        }
        __syncthreads();
        if (c == 0) {
            float s = 0.f;
#pragma unroll
            for (int j = 0; j < 16; j++) s += red[j];
            nebuf[n] = s;
        }
    }
}

// ---------------- final per-graph energy reduction ----------------
__global__ __launch_bounds__(256) void k_reduceE(
    const float* __restrict__ e0buf, const float* __restrict__ nebuf,
    const int* __restrict__ gs, float* __restrict__ Eout)
{
    int b = blockIdx.x, t = threadIdx.x;
    int n0 = gs[b], n1 = gs[b + 1];
    float s = 0.f;
    for (int n = n0 + t; n < n1; n += 256)
        s += e0buf[n] + nebuf[n] + nebuf[NA + n];
#pragma unroll
    for (int o = 32; o; o >>= 1) s += __shfl_down(s, o, 64);
    __shared__ float red[4];
    if ((t & 63) == 0) red[t >> 6] = s;
    __syncthreads();
    if (t == 0) Eout[b] = red[0] + red[1] + red[2] + red[3];
}

// ---------------- workspace layout (floats) ----------------
constexpr size_t NAC   = (size_t)NA * C;
constexpr size_t F_COSD = 0;
constexpr size_t F_SIND = F_COSD + (size_t)NA * NKP;
constexpr size_t F_Y    = F_SIND + (size_t)NA * NKP;
constexpr size_t F_EF   = F_Y + (size_t)NE * 16;
constexpr size_t F_H    = F_EF + (size_t)NE * 8;
constexpr size_t F_HN   = F_H + NAC;
constexpr size_t F_HRES = F_HN + NAC;
constexpr size_t F_T1   = F_HRES + NAC;
constexpr size_t F_HE2  = F_T1 + NAC;
constexpr size_t F_HU   = F_HE2 + NAC;
constexpr size_t F_TA   = F_HU + NAC;
constexpr size_t F_TB   = F_TA + (size_t)NE * 64;
constexpr size_t F_WTS  = F_TB + (size_t)NE * 64;
constexpr size_t F_W    = F_WTS + 128 * 1024;
constexpr size_t F_SFR  = F_W + (size_t)NE * 512;
constexpr size_t F_SFI  = F_SFR + SFSZ;
constexpr size_t F_SFP  = F_SFI + SFSZ;
constexpr size_t F_KD   = F_SFP + 2 * (size_t)SFSPLIT * SFSZ;
constexpr size_t F_E0   = F_KD + 1024;
constexpr size_t F_NE   = F_E0 + NA;
constexpr size_t F_CB   = F_NE + 2 * (size_t)NA;
constexpr size_t F_SB   = F_CB + (size_t)NA * 64;
constexpr size_t F_END  = F_SB + (size_t)NA * 64;
constexpr size_t I_BASE = ((F_END * 4 + 255) / 256) * 256;

extern "C" void kernel_launch(void* const* d_in, const int* in_sizes, int n_in,
                              void* d_out, int out_size, void* d_ws, size_t ws_size,
                              hipStream_t stream) {
    const float* pos    = (const float*)d_in[0];
    const float* na     = (const float*)d_in[1];
    const float* shifts = (const float*)d_in[2];
    const int*   eidx   = (const int*)d_in[3];
    const int*   batch  = (const int*)d_in[4];
    const float* kgrid  = (const float*)d_in[5];
    const float* krbf   = (const float*)d_in[6];
    const float* Wemb   = (const float*)d_in[7];
    const float* aE     = (const float*)d_in[8];
    const float* rW1    = (const float*)d_in[9];
    const float* rb1    = (const float*)d_in[10];
    const float* rW2    = (const float*)d_in[11];
    const float* rb2    = (const float*)d_in[12];
    const float* rW3    = (const float*)d_in[13];
    const float* rb3    = (const float*)d_in[14];
    const float* rW4    = (const float*)d_in[15];
    const float* Wup    = (const float*)d_in[16];
    const float* w2     = (const float*)d_in[17];
    const float* w3     = (const float*)d_in[18];
    const float* Wmix   = (const float*)d_in[19];
    const float* Wr0    = (const float*)d_in[20];
    const float* Wr1a   = (const float*)d_in[21];
    const float* Wr1b   = (const float*)d_in[22];
    const float* Wdown  = (const float*)d_in[23];
    const float* WupE   = (const float*)d_in[24];
    const float* Wpre1  = (const float*)d_in[25];
    const float* bpre1  = (const float*)d_in[26];
    const float* Wpre2  = (const float*)d_in[27];
    const float* bpre2  = (const float*)d_in[28];
    const float* Wm1    = (const float*)d_in[29];
    const float* bm1    = (const float*)d_in[30];
    const float* Wm2    = (const float*)d_in[31];
    const float* bm2    = (const float*)d_in[32];

    float* fw = (float*)d_ws;
    float* cosd = fw + F_COSD;
    float* sind = fw + F_SIND;
    float* Ybuf = fw + F_Y;
    float* efb  = fw + F_EF;
    float* h    = fw + F_H;
    float* hn   = fw + F_HN;
    float* hres = fw + F_HRES;
    float* he2  = fw + F_HE2;
    float* hu   = fw + F_HU;
    unsigned short* W4bt = (unsigned short*)(fw + F_WTS);
    unsigned short* W2bt  = W4bt + (size_t)2 * 512 * 64;
    unsigned short* W3bt  = W2bt + (size_t)2 * 64 * 64;
    unsigned short* Wm1bt = W3bt + (size_t)2 * 64 * 64;
    unsigned short* Wm2bt = Wm1bt + (size_t)2 * 128 * 128;
    unsigned short* Wp1bt = Wm2bt + (size_t)2 * 128 * 128;
    unsigned short* Wp2bt = Wp1bt + (size_t)2 * 128 * 128;
    unsigned short* Wupbt = Wp2bt + (size_t)2 * 128 * 128;
    unsigned short* W1bt  = Wupbt + (size_t)2 * 128 * 128;
    unsigned short* wbuf = (unsigned short*)(fw + F_W);
    unsigned short* sfrT = (unsigned short*)(fw + F_SFR);
    unsigned short* sfiT = (unsigned short*)(fw + F_SFI);
    float* sfp  = fw + F_SFP;
    float* kdwn = fw + F_KD;
    float* e0buf = fw + F_E0;
    float* nebuf = fw + F_NE;
    unsigned short* cosdb = (unsigned short*)(fw + F_CB);
    unsigned short* sindb = (unsigned short*)(fw + F_SB);

    int* ip     = (int*)((char*)d_ws + I_BASE);
    int* deg    = ip;
    int* offs   = ip + NA;
    int* cursor = ip + 2 * NA + 1;
    int* perm   = ip + 3 * NA + 1;
    int* srcP   = perm + NE;
    int* gs     = srcP + NE;

    float* Eout = (float*)d_out;

    hipMemsetAsync(deg, 0, NA * sizeof(int), stream);

    k_setup<<<TKEND, 128, 0, stream>>>(
        na, Wemb, aE, batch, pos, kgrid, krbf, Wdown,
        rW4, rW2, rW3, rW1, Wm1, Wm2, Wpre1, Wpre2, Wup,
        h, e0buf, cosd, sind, cosdb, sindb, kdwn,
        W4bt, W2bt, W3bt, W1bt, Wm1bt, Wm2bt, Wp1bt, Wp2bt, Wupbt, gs);
    k_count<<<NE / 256, 256, 0, stream>>>(eidx, deg);
    k_scan<<<1, 1024, 0, stream>>>(deg, offs, cursor);
    k_fill<<<NE / 256, 256, 0, stream>>>(eidx, cursor, perm, srcP);
    k_edge_geom<<<NE / 256, 256, 0, stream>>>(pos, shifts, eidx, perm, Ybuf, efb);

    // ---- edge branch: one fused kernel, both layers, chunk-parallel ----
    k_edge_mlp<<<dim3(2 * NE / 64, 8), 256, 0, stream>>>(efb, W1bt, rb1, W2bt, rb2,
                                                         W3bt, rb3, W4bt, wbuf);

    const dim3 gSF(BG, 4, SFSPLIT);
    const dim3 gRT(8, BG);
    const dim3 gHE(16, BG);

    for (int i = 0; i < 2; i++) {
        const float* bpre1_i = bpre1 + (size_t)i * C;
        const float* bpre2_i = bpre2 + (size_t)i * C;
        const float* WupE_i  = WupE + (size_t)i * 8 * C;
        const float* bm1_i   = bm1 + (size_t)i * C;
        const float* bm2_i   = bm2 + (size_t)i * C;
        const float* w2_i    = w2 + (size_t)i * 4 * C;
        const float* w3_i    = w3 + (size_t)i * 4 * C;
        const float* Wmix_i  = Wmix + (size_t)i * C * C;
        const unsigned short* Wm1bt_i = Wm1bt + (size_t)i * 128 * 128;
        const unsigned short* Wm2bt_i = Wm2bt + (size_t)i * 128 * 128;
        const unsigned short* Wp1bt_i = Wp1bt + (size_t)i * 128 * 128;
        const unsigned short* Wp2bt_i = Wp2bt + (size_t)i * 128 * 128;
        const unsigned short* Wupbt_i = Wupbt + (size_t)i * 128 * 128;
        const unsigned short* wbuf_i = wbuf + (size_t)i * NE * 512;

        // fused pre-MLP + Wup
        k_pre<<<NA / 32, 256, 0, stream>>>(h, Wp1bt_i, bpre1_i, Wupbt_i,
                                           Wp2bt_i, bpre2_i, hu, hres);

        // Ewald branch: sf -> sfredT -> fused MFMA (he + he-MLP)
        k_sf<<<gSF, 256, 0, stream>>>(hres, cosd, sind, gs, kdwn, WupE_i, sfp);
        k_sfredT<<<gRT, 256, 0, stream>>>(sfp, sfrT, sfiT);
        k_he_mlp<<<gHE, 256, 0, stream>>>(cosdb, sindb, sfrT, sfiT, gs,
                                          Wm1bt_i, bm1_i, Wm2bt_i, bm2_i, he2);

        // fused gather (sequential) + Wmix + residual + energy
        k_gather_mix<<<NA, 128, 0, stream>>>(wbuf_i, hu, Ybuf, srcP, offs,
                                             w2_i, w3_i, Wmix_i, h, he2,
                                             Wr0, Wr1a, Wr1b, (i == 0) ? 0 : 1,
                                             hn, nebuf + (size_t)i * NA);

        float* tmp = h; h = hn; hn = tmp;
    }

    k_reduceE<<<BG, 256, 0, stream>>>(e0buf, nebuf, gs, Eout);
}

// Round 20
// 306.058 us; speedup vs baseline: 1.2988x; 1.2988x over previous
//
#include <hip/hip_runtime.h>
#include <hip/hip_bf16.h>
#include <math.h>

// ---------------- problem constants ----------------
constexpr int NA  = 3200;     // atoms
constexpr int NE  = 51200;    // edges
constexpr int C   = 128;      // channels
constexpr int NK  = 123;      // k-points with |k| <= 0.6
constexpr int NKP = 128;      // padded stride
constexpr int BG  = 8;        // graphs
constexpr int SFSPLIT = 8;    // k_sf split factor
constexpr float SKIPF = 0.57735026918962576f;  // 3^-0.5
constexpr float AVGN  = 16.0f;
constexpr size_t SFSZ = (size_t)BG * NK * C;   // one sf plane (125952)

__device__ __forceinline__ float dsilu(float x) { return x / (1.0f + expf(-x)); }

__device__ __forceinline__ unsigned short f2bf(float f) {
    unsigned int u = __float_as_uint(f);
    unsigned int r = (u + 0x7fffu + ((u >> 16) & 1u)) >> 16;
    return (unsigned short)r;
}
__device__ __forceinline__ float bf2f(unsigned short s) {
    return __uint_as_float(((unsigned int)s) << 16);
}

typedef __attribute__((ext_vector_type(8))) short short8;
typedef __attribute__((ext_vector_type(4))) float f32x4;

// ---------------- fused pre-MLP + Wup (3-stage bf16 MFMA, 32 rows/block) ----------------
__global__ __launch_bounds__(256, 2) void k_pre(
    const float* __restrict__ h,
    const unsigned short* __restrict__ W1t, const float* __restrict__ b1,
    const unsigned short* __restrict__ Wut,
    const unsigned short* __restrict__ W2t, const float* __restrict__ b2,
    float* __restrict__ hu, float* __restrict__ hres)
{
    constexpr int MT = 32, ASH = 136;
    __shared__ unsigned short Xs[MT * ASH];
    __shared__ unsigned short Ts[MT * ASH];
    __shared__ unsigned short Ws[128 * ASH];
    const int tid = threadIdx.x;
    const int m0 = blockIdx.x * MT;

    for (int idx = tid; idx < MT * 32; idx += 256) {
        int r = idx >> 5, c4 = idx & 31;
        float4 v = ((const float4*)h)[(size_t)(m0 + r) * 32 + c4];
        ushort4 pk;
        pk.x = f2bf(v.x); pk.y = f2bf(v.y); pk.z = f2bf(v.z); pk.w = f2bf(v.w);
        *(ushort4*)(Xs + r * ASH + c4 * 4) = pk;
    }
    for (int idx = tid; idx < 128 * 16; idx += 256) {
        int r = idx >> 4, s = idx & 15;
        *(short8*)(Ws + r * ASH + s * 8) = ((const short8*)W1t)[(size_t)r * 16 + s];
    }
    __syncthreads();

    const int wave = tid >> 6;
    const int lane = tid & 63;
    const int q = lane >> 4;
    const int l16 = lane & 15;
    const int mh = (wave & 1) * 16;
    const int nh = (wave >> 1) * 64;

    f32x4 acc[4];
#pragma unroll
    for (int ni = 0; ni < 4; ni++) acc[ni] = (f32x4){0.f, 0.f, 0.f, 0.f};
#pragma unroll
    for (int kc = 0; kc < 4; kc++) {
        short8 a = *(const short8*)(Xs + (mh + l16) * ASH + kc * 32 + q * 8);
#pragma unroll
        for (int ni = 0; ni < 4; ni++) {
            short8 b = *(const short8*)(Ws + (nh + ni * 16 + l16) * ASH + kc * 32 + q * 8);
            acc[ni] = __builtin_amdgcn_mfma_f32_16x16x32_bf16(a, b, acc[ni], 0, 0, 0);
        }
    }
#pragma unroll
    for (int ni = 0; ni < 4; ni++) {
        float bv = b1[nh + ni * 16 + l16];
#pragma unroll
        for (int r = 0; r < 4; r++)
            Ts[(mh + q * 4 + r) * ASH + nh + ni * 16 + l16] = f2bf(dsilu(acc[ni][r] + bv));
    }
    __syncthreads();
    for (int idx = tid; idx < 128 * 16; idx += 256) {
        int r = idx >> 4, s = idx & 15;
        *(short8*)(Ws + r * ASH + s * 8) = ((const short8*)Wut)[(size_t)r * 16 + s];
    }
    __syncthreads();
#pragma unroll
    for (int ni = 0; ni < 4; ni++) acc[ni] = (f32x4){0.f, 0.f, 0.f, 0.f};
#pragma unroll
    for (int kc = 0; kc < 4; kc++) {
        short8 a = *(const short8*)(Xs + (mh + l16) * ASH + kc * 32 + q * 8);
#pragma unroll
        for (int ni = 0; ni < 4; ni++) {
            short8 b = *(const short8*)(Ws + (nh + ni * 16 + l16) * ASH + kc * 32 + q * 8);
            acc[ni] = __builtin_amdgcn_mfma_f32_16x16x32_bf16(a, b, acc[ni], 0, 0, 0);
        }
    }
#pragma unroll
    for (int ni = 0; ni < 4; ni++) {
#pragma unroll
        for (int r = 0; r < 4; r++)
            hu[(size_t)(m0 + mh + q * 4 + r) * C + nh + ni * 16 + l16] = acc[ni][r];
    }
    __syncthreads();
    for (int idx = tid; idx < 128 * 16; idx += 256) {
        int r = idx >> 4, s = idx & 15;
        *(short8*)(Ws + r * ASH + s * 8) = ((const short8*)W2t)[(size_t)r * 16 + s];
    }
    __syncthreads();
#pragma unroll
    for (int ni = 0; ni < 4; ni++) acc[ni] = (f32x4){0.f, 0.f, 0.f, 0.f};
#pragma unroll
    for (int kc = 0; kc < 4; kc++) {
        short8 a = *(const short8*)(Ts + (mh + l16) * ASH + kc * 32 + q * 8);
#pragma unroll
        for (int ni = 0; ni < 4; ni++) {
            short8 b = *(const short8*)(Ws + (nh + ni * 16 + l16) * ASH + kc * 32 + q * 8);
            acc[ni] = __builtin_amdgcn_mfma_f32_16x16x32_bf16(a, b, acc[ni], 0, 0, 0);
        }
    }
#pragma unroll
    for (int ni = 0; ni < 4; ni++) {
        float bv = b2[nh + ni * 16 + l16];
#pragma unroll
        for (int r = 0; r < 4; r++) {
            int row = m0 + mh + q * 4 + r;
            int col = nh + ni * 16 + l16;
            hres[(size_t)row * C + col] = acc[ni][r] + bv + h[(size_t)row * C + col];
        }
    }
}

// ---------------- fused edge geometry + MLP: ef(8)->64->64->64->512, bf16 MFMA ----------------
// MT=64 rows/block, 32 KB LDS -> 5 blocks/CU. grid: 2*NE/64 blocks of 256 thr.
// Geometry computed inline (tid<64); layer-0 blocks also store Y.
__global__ __launch_bounds__(256, 4) void k_edge_mlp(
    const float* __restrict__ pos, const float* __restrict__ shifts,
    const int* __restrict__ eidx, const int* __restrict__ perm,
    const unsigned short* __restrict__ W1bt, const float* __restrict__ rb1,
    const unsigned short* __restrict__ W2bt, const float* __restrict__ rb2,
    const unsigned short* __restrict__ W3bt, const float* __restrict__ rb3,
    const unsigned short* __restrict__ W4bt,
    unsigned short* __restrict__ wbuf, float* __restrict__ Y)
{
    constexpr int MT = 64;
    constexpr int TS = 72;    // T1/T2/WB row stride (shorts)
    constexpr int AS0 = 40;   // A0 row stride (shorts), K=32 padded
    __shared__ __align__(16) char smem[32768];
    unsigned short* A0 = (unsigned short*)smem;            // 64*40*2 = 5120
    unsigned short* T1 = (unsigned short*)(smem + 5120);   // 64*72*2 = 9216
    unsigned short* T2 = (unsigned short*)(smem + 14336);  // 9216
    unsigned short* WB = (unsigned short*)(smem + 23552);  // 9216
    const int tid = threadIdx.x;
    const int nb = NE / MT;
    const int layer = (blockIdx.x >= nb) ? 1 : 0;
    const size_t m0 = (size_t)(blockIdx.x - layer * nb) * MT;

    // ---- inline geometry for this block's 64 slots ----
    if (tid < 64) {
        int j = (int)m0 + tid;
        int e = perm[j];
        int si = eidx[e], di = eidx[NE + e];
        float vx = pos[di * 3 + 0] - pos[si * 3 + 0] + shifts[e * 3 + 0];
        float vy = pos[di * 3 + 1] - pos[si * 3 + 1] + shifts[e * 3 + 1];
        float vz = pos[di * 3 + 2] - pos[si * 3 + 2] + shifts[e * 3 + 2];
        float r = sqrtf(vx * vx + vy * vy + vz * vz);
        float rinv = 1.0f / fmaxf(r, 1e-9f);
        float x = vx * rinv, y = vy * rinv, z = vz * rinv;

        const float s3 = 1.7320508075688772f, s5 = 2.2360679774997896f, s15 = 3.8729833462074170f;
        const float c70 = 2.0916500663351889f;
        const float c105 = 10.246950765959598f;
        const float c42 = 1.6201851746019651f;
        const float c7 = 1.3228756555322954f;
        float o[16];
        o[0] = 1.0f;
        o[1] = s3 * x; o[2] = s3 * y; o[3] = s3 * z;
        o[4] = s15 * x * y; o[5] = s15 * y * z; o[6] = 0.5f * s5 * (3.f * z * z - 1.f);
        o[7] = s15 * x * z; o[8] = 0.5f * s15 * (x * x - y * y);
        o[9]  = c70 * y * (3.f * x * x - y * y);
        o[10] = c105 * x * y * z;
        o[11] = c42 * y * (5.f * z * z - 1.f);
        o[12] = c7 * z * (5.f * z * z - 3.f);
        o[13] = c42 * x * (5.f * z * z - 1.f);
        o[14] = 0.5f * c105 * z * (x * x - y * y);
        o[15] = c70 * x * (x * x - 3.f * y * y);
        if (layer == 0) {
            float4* Y4 = (float4*)(Y + (size_t)j * 16);
            Y4[0] = make_float4(o[0], o[1], o[2], o[3]);
            Y4[1] = make_float4(o[4], o[5], o[6], o[7]);
            Y4[2] = make_float4(o[8], o[9], o[10], o[11]);
            Y4[3] = make_float4(o[12], o[13], o[14], o[15]);
        }
        float uu = fminf(fmaxf(r * 0.2f, 0.f), 1.f);
        float u2 = uu * uu, u4 = u2 * u2, u5 = u4 * uu, u6 = u5 * uu, u7 = u6 * uu;
        float env = 1.f - 21.f * u5 + 35.f * u6 - 15.f * u7;
        env = (r < 5.0f) ? env : 0.0f;
        float pref = 0.63245553203367587f * rinv * env;
        const float pio5 = 0.62831853071795865f;
        float efv[8];
#pragma unroll
        for (int n1 = 1; n1 <= 8; n1++) efv[n1 - 1] = pref * sinf(n1 * pio5 * r);
        ushort4 pk0, pk1;
        pk0.x = f2bf(efv[0]); pk0.y = f2bf(efv[1]); pk0.z = f2bf(efv[2]); pk0.w = f2bf(efv[3]);
        pk1.x = f2bf(efv[4]); pk1.y = f2bf(efv[5]); pk1.z = f2bf(efv[6]); pk1.w = f2bf(efv[7]);
        *(ushort4*)(A0 + tid * AS0 + 0) = pk0;
        *(ushort4*)(A0 + tid * AS0 + 4) = pk1;
    }
    const short8 z8 = (short8){0,0,0,0,0,0,0,0};
    if (tid < 192) {
        int r = tid / 3, s = tid - r * 3;
        *(short8*)(A0 + r * AS0 + 8 + s * 8) = z8;
    }
    // load W1 ([64][32])
    {
        int r = tid >> 2, s = tid & 3;
        *(short8*)(WB + r * TS + s * 8) =
            ((const short8*)(W1bt + (size_t)layer * 64 * 32))[r * 4 + s];
    }
    __syncthreads();

    const int wave = tid >> 6;
    const int lane = tid & 63;
    const int q = lane >> 4;
    const int l16 = lane & 15;
    const int mw = wave * 16;   // 4 waves x 16 rows = 64 rows

    const float* b1 = rb1 + layer * 64;
    const float* b2 = rb2 + layer * 64;
    const float* b3 = rb3 + layer * 64;

    f32x4 acc[4];
    // ---- stage 1: K=32 ----
#pragma unroll
    for (int ni = 0; ni < 4; ni++) acc[ni] = (f32x4){0.f, 0.f, 0.f, 0.f};
    {
        short8 a = *(const short8*)(A0 + (mw + l16) * AS0 + q * 8);
#pragma unroll
        for (int ni = 0; ni < 4; ni++) {
            short8 b = *(const short8*)(WB + (ni * 16 + l16) * TS + q * 8);
            acc[ni] = __builtin_amdgcn_mfma_f32_16x16x32_bf16(a, b, acc[ni], 0, 0, 0);
        }
    }
#pragma unroll
    for (int ni = 0; ni < 4; ni++) {
        float bv = b1[ni * 16 + l16];
#pragma unroll
        for (int r = 0; r < 4; r++)
            T1[(mw + q * 4 + r) * TS + ni * 16 + l16] = f2bf(dsilu(acc[ni][r] + bv));
    }
    __syncthreads();
    // ---- stage 2: W2, K=64, T1 -> T2 ----
    for (int idx = tid; idx < 512; idx += 256) {
        int r = idx >> 3, s = idx & 7;
        *(short8*)(WB + r * TS + s * 8) =
            ((const short8*)(W2bt + (size_t)layer * 64 * 64))[r * 8 + s];
    }
    __syncthreads();
#pragma unroll
    for (int ni = 0; ni < 4; ni++) acc[ni] = (f32x4){0.f, 0.f, 0.f, 0.f};
#pragma unroll
    for (int kc = 0; kc < 2; kc++) {
        short8 a = *(const short8*)(T1 + (mw + l16) * TS + kc * 32 + q * 8);
#pragma unroll
        for (int ni = 0; ni < 4; ni++) {
            short8 b = *(const short8*)(WB + (ni * 16 + l16) * TS + kc * 32 + q * 8);
            acc[ni] = __builtin_amdgcn_mfma_f32_16x16x32_bf16(a, b, acc[ni], 0, 0, 0);
        }
    }
#pragma unroll
    for (int ni = 0; ni < 4; ni++) {
        float bv = b2[ni * 16 + l16];
#pragma unroll
        for (int r = 0; r < 4; r++)
            T2[(mw + q * 4 + r) * TS + ni * 16 + l16] = f2bf(dsilu(acc[ni][r] + bv));
    }
    __syncthreads();
    // ---- stage 3: W3, K=64, T2 -> T1 ----
    for (int idx = tid; idx < 512; idx += 256) {
        int r = idx >> 3, s = idx & 7;
        *(short8*)(WB + r * TS + s * 8) =
            ((const short8*)(W3bt + (size_t)layer * 64 * 64))[r * 8 + s];
    }
    __syncthreads();
#pragma unroll
    for (int ni = 0; ni < 4; ni++) acc[ni] = (f32x4){0.f, 0.f, 0.f, 0.f};
#pragma unroll
    for (int kc = 0; kc < 2; kc++) {
        short8 a = *(const short8*)(T2 + (mw + l16) * TS + kc * 32 + q * 8);
#pragma unroll
        for (int ni = 0; ni < 4; ni++) {
            short8 b = *(const short8*)(WB + (ni * 16 + l16) * TS + kc * 32 + q * 8);
            acc[ni] = __builtin_amdgcn_mfma_f32_16x16x32_bf16(a, b, acc[ni], 0, 0, 0);
        }
    }
#pragma unroll
    for (int ni = 0; ni < 4; ni++) {
        float bv = b3[ni * 16 + l16];
#pragma unroll
        for (int r = 0; r < 4; r++)
            T1[(mw + q * 4 + r) * TS + ni * 16 + l16] = f2bf(dsilu(acc[ni][r] + bv));
    }

    // ---- stage 4: W4 in 8 n-chunks of 64, direct stores (R15/R18 structure) ----
    const unsigned short* W4l = W4bt + (size_t)layer * 512 * 64;
    unsigned short* wout = wbuf + ((size_t)layer * NE + m0) * 512;
#pragma unroll 1
    for (int nt = 0; nt < 8; nt++) {
        __syncthreads();
        for (int idx = tid; idx < 512; idx += 256) {
            int r = idx >> 3, s = idx & 7;
            *(short8*)(WB + r * TS + s * 8) = ((const short8*)W4l)[(nt * 64 + r) * 8 + s];
        }
        __syncthreads();
#pragma unroll
        for (int ni = 0; ni < 4; ni++) acc[ni] = (f32x4){0.f, 0.f, 0.f, 0.f};
#pragma unroll
        for (int kc = 0; kc < 2; kc++) {
            short8 a = *(const short8*)(T1 + (mw + l16) * TS + kc * 32 + q * 8);
#pragma unroll
            for (int ni = 0; ni < 4; ni++) {
                short8 b = *(const short8*)(WB + (ni * 16 + l16) * TS + kc * 32 + q * 8);
                acc[ni] = __builtin_amdgcn_mfma_f32_16x16x32_bf16(a, b, acc[ni], 0, 0, 0);
            }
        }
#pragma unroll
        for (int ni = 0; ni < 4; ni++)
#pragma unroll
            for (int r = 0; r < 4; r++) {
                int row = mw + q * 4 + r;
                int col = nt * 64 + ni * 16 + l16;
                wout[(size_t)row * 512 + col] = f2bf(acc[ni][r]);
            }
    }
}

// ---------------- setup megakernel (now also does degree count) ----------------
constexpr int TK0 = NA;
constexpr int TK1 = TK0 + 8;
constexpr int TK2 = TK1 + 512;
constexpr int TK3 = TK2 + 64;
constexpr int TK4 = TK3 + 64;
constexpr int TK4b = TK4 + 32;     // W1 padded bf16
constexpr int TK5 = TK4b + 256;
constexpr int TK6 = TK5 + 256;
constexpr int TK7 = TK6 + 256;
constexpr int TK8 = TK7 + 256;
constexpr int TK9 = TK8 + 256;
constexpr int TKA = TK9 + 1;       // gs task
constexpr int TKEND = TKA + NE / 128;  // degree-count tasks (400 blocks)

__device__ __forceinline__ float sincn(float x) {
    float px = 3.14159265358979323846f * x;
    return (fabsf(px) < 1e-8f) ? 1.0f : (sinf(px) / px);
}

__device__ __forceinline__ void convT128_task(
    const float* __restrict__ W, unsigned short* __restrict__ Wt, int idx)
{
    int layer = idx >> 14, rem = idx & 16383;
    int n = rem >> 7, k = rem & 127;
    Wt[((size_t)layer << 14) + (n << 7) + k] = f2bf(W[((size_t)layer << 14) + (k << 7) + n]);
}

__global__ __launch_bounds__(128) void k_setup(
    const float* __restrict__ na, const float* __restrict__ Wemb,
    const float* __restrict__ aE, const int* __restrict__ batch,
    const float* __restrict__ pos, const float* __restrict__ kgrid,
    const float* __restrict__ krbf, const float* __restrict__ Wdown,
    const float* __restrict__ rW4, const float* __restrict__ rW2,
    const float* __restrict__ rW3, const float* __restrict__ rW1,
    const float* __restrict__ Wm1, const float* __restrict__ Wm2,
    const float* __restrict__ Wpre1, const float* __restrict__ Wpre2,
    const float* __restrict__ Wup, const int* __restrict__ eidx,
    float* __restrict__ h, float* __restrict__ e0buf,
    float* __restrict__ cosd, float* __restrict__ sind,
    unsigned short* __restrict__ cosdb, unsigned short* __restrict__ sindb,
    float* __restrict__ kdwn,
    unsigned short* __restrict__ W4bt, unsigned short* __restrict__ W2bt,
    unsigned short* __restrict__ W3bt, unsigned short* __restrict__ W1bt,
    unsigned short* __restrict__ Wm1bt, unsigned short* __restrict__ Wm2bt,
    unsigned short* __restrict__ Wpre1bt, unsigned short* __restrict__ Wpre2bt,
    unsigned short* __restrict__ Wupbt,
    int* __restrict__ gs, int* __restrict__ deg)
{
    const int bx = blockIdx.x;
    const int t = threadIdx.x;
    __shared__ int cnt[BG];

    if (bx < TK0) {
        int n = bx, c = t;
        float s = 0.f;
#pragma unroll
        for (int k = 0; k < 10; k++) s += na[n * 10 + k] * Wemb[k * C + c];
        h[(size_t)n * C + c] = s;
        if (c == 0) {
            float e = 0.f;
#pragma unroll
            for (int k = 0; k < 10; k++) e += na[n * 10 + k] * aE[k];
            e0buf[n] = e;
        }
        float p0 = pos[n * 3 + 0], p1 = pos[n * 3 + 1], p2 = pos[n * 3 + 2];
        float sd = sincn(0.1f * p0) * sincn(0.1f * p1) * sincn(0.1f * p2);
        int k = t;
        float cv = 0.f, sv = 0.f;
        if (k < NK) {
            float d = p0 * kgrid[k * 3 + 0] + p1 * kgrid[k * 3 + 1] + p2 * kgrid[k * 3 + 2];
            float sn, cs;
            sincosf(d, &sn, &cs);
            cv = sd * cs;
            sv = sd * sn;
        }
        cosd[(size_t)n * NKP + k] = cv;
        sind[(size_t)n * NKP + k] = sv;
        cosdb[(size_t)n * NKP + k] = f2bf(cv);
        sindb[(size_t)n * NKP + k] = f2bf(sv);
    } else if (bx < TK1) {
        int slot = (bx - TK0) * 128 + t;
        if (slot < NK * 8) {
            int k = slot >> 3, j = slot & 7;
            float s = 0.f;
            for (int r = 0; r < 128; r++) s += krbf[k * 128 + r] * Wdown[r * 8 + j];
            kdwn[slot] = s;
        }
    } else if (bx < TK2) {
        int idx = (bx - TK1) * 128 + t;
        int layer = idx >> 15, rem = idx & 32767;
        int n = rem >> 6, k = rem & 63;
        W4bt[((size_t)layer * 512 + n) * 64 + k] = f2bf(rW4[((size_t)layer * 64 + k) * 512 + n]);
    } else if (bx < TK3) {
        int idx = (bx - TK2) * 128 + t;
        int layer = idx >> 12, rem = idx & 4095;
        int n = rem >> 6, k = rem & 63;
        W2bt[((size_t)layer * 64 + n) * 64 + k] = f2bf(rW2[((size_t)layer * 64 + k) * 64 + n]);
    } else if (bx < TK4) {
        int idx = (bx - TK3) * 128 + t;
        int layer = idx >> 12, rem = idx & 4095;
        int n = rem >> 6, k = rem & 63;
        W3bt[((size_t)layer * 64 + n) * 64 + k] = f2bf(rW3[((size_t)layer * 64 + k) * 64 + n]);
    } else if (bx < TK4b) {
        int idx = (bx - TK4) * 128 + t;   // over 2*64*32
        int layer = idx >> 11, rem = idx & 2047;
        int n = rem >> 5, k = rem & 31;
        W1bt[((size_t)layer * 64 + n) * 32 + k] =
            (k < 8) ? f2bf(rW1[((size_t)layer * 8 + k) * 64 + n]) : (unsigned short)0;
    } else if (bx < TK5) {
        convT128_task(Wm1, Wm1bt, (bx - TK4b) * 128 + t);
    } else if (bx < TK6) {
        convT128_task(Wm2, Wm2bt, (bx - TK5) * 128 + t);
    } else if (bx < TK7) {
        convT128_task(Wpre1, Wpre1bt, (bx - TK6) * 128 + t);
    } else if (bx < TK8) {
        convT128_task(Wpre2, Wpre2bt, (bx - TK7) * 128 + t);
    } else if (bx < TK9) {
        convT128_task(Wup, Wupbt, (bx - TK8) * 128 + t);
    } else if (bx < TKA) {
        if (t < BG) cnt[t] = 0;
        __syncthreads();
        for (int n = t; n < NA; n += 128) atomicAdd(&cnt[batch[n]], 1);
        __syncthreads();
        if (t == 0) {
            int s = 0;
            for (int b = 0; b < BG; b++) { gs[b] = s; s += cnt[b]; }
            gs[BG] = s;
        }
    } else {
        int e = (bx - TKA) * 128 + t;
        if (e < NE) atomicAdd(&deg[eidx[NE + e]], 1);
    }
}

// ---------------- CSR by dst ----------------
__global__ __launch_bounds__(1024) void k_scan(
    const int* __restrict__ deg, int* __restrict__ offs, int* __restrict__ cursor)
{
    __shared__ int sc[1024];
    int tid = threadIdx.x;
    int base = tid * 4;
    int v[4]; int s = 0;
#pragma unroll
    for (int i = 0; i < 4; i++) {
        int idx = base + i;
        int d = (idx < NA) ? deg[idx] : 0;
        v[i] = s; s += d;
    }
    sc[tid] = s;
    __syncthreads();
    for (int ofs = 1; ofs < 1024; ofs <<= 1) {
        int t = (tid >= ofs) ? sc[tid - ofs] : 0;
        __syncthreads();
        sc[tid] += t;
        __syncthreads();
    }
    int excl = (tid > 0) ? sc[tid - 1] : 0;
#pragma unroll
    for (int i = 0; i < 4; i++) {
        int idx = base + i;
        if (idx < NA) { int o = excl + v[i]; offs[idx] = o; cursor[idx] = o; }
    }
    if (tid == 1023) offs[NA] = sc[1023];
}

// fill: perm[p] = e, srcP[p] = src(e)
__global__ __launch_bounds__(256) void k_fill(
    const int* __restrict__ eidx, int* __restrict__ cursor,
    int* __restrict__ perm, int* __restrict__ srcP)
{
    int e = blockIdx.x * 256 + threadIdx.x;
    if (e < NE) {
        int d = eidx[NE + e];
        int p = atomicAdd(&cursor[d], 1);
        perm[p] = e;
        srcP[p] = eidx[e];
    }
}

// ---------------- Ewald: structure-factor partials (kfilter fused inline) ----------------
__global__ __launch_bounds__(256, 4) void k_sf(
    const float* __restrict__ hres, const float* __restrict__ cosd, const float* __restrict__ sind,
    const int* __restrict__ gs, const float* __restrict__ kdwn, const float* __restrict__ WupE,
    float* __restrict__ sfp)
{
    const int b = blockIdx.x, kt = blockIdx.y, sp = blockIdx.z;
    const int n0 = gs[b], n1 = gs[b + 1];
    const int cnt = n1 - n0;
    const int per = (cnt + SFSPLIT - 1) / SFSPLIT;
    const int cs = n0 + sp * per;
    const int ce = min(cs + per, n1);

    __shared__ float Hs[32 * 128];
    __shared__ float Cs[32 * 32];
    __shared__ float Ss[32 * 32];

    const int tid = threadIdx.x;
    const int tx = tid & 31;
    const int ty = tid >> 5;

    float accR[4][4], accI[4][4];
#pragma unroll
    for (int i = 0; i < 4; i++)
#pragma unroll
        for (int j = 0; j < 4; j++) { accR[i][j] = 0.f; accI[i][j] = 0.f; }

    float4* H4 = (float4*)Hs;
    float4* C4 = (float4*)Cs;
    float4* S4 = (float4*)Ss;

    for (int nb = cs; nb < ce; nb += 32) {
        __syncthreads();
        for (int idx = tid; idx < 32 * 32; idx += 256) {
            int r = idx >> 5, c4 = idx & 31;
            int n = nb + r;
            H4[idx] = (n < ce) ? ((const float4*)hres)[(size_t)n * 32 + c4]
                               : make_float4(0.f, 0.f, 0.f, 0.f);
        }
        for (int idx = tid; idx < 32 * 8; idx += 256) {
            int r = idx >> 3, k4 = idx & 7;
            int n = nb + r;
            float4 cv = make_float4(0.f, 0.f, 0.f, 0.f), sv = cv;
            if (n < ce) {
                cv = ((const float4*)cosd)[(size_t)n * 32 + kt * 8 + k4];
                sv = ((const float4*)sind)[(size_t)n * 32 + kt * 8 + k4];
            }
            C4[idx] = cv;
            S4[idx] = sv;
        }
        __syncthreads();
        const int lim = min(32, ce - nb);
        for (int n = 0; n < lim; n++) {
            float4 hv = H4[n * 32 + tx];
            float4 cv = C4[n * 8 + ty];
            float4 sv = S4[n * 8 + ty];
            float h[4] = { hv.x, hv.y, hv.z, hv.w };
            float ck[4] = { cv.x, cv.y, cv.z, cv.w };
            float sk[4] = { sv.x, sv.y, sv.z, sv.w };
#pragma unroll
            for (int i = 0; i < 4; i++)
#pragma unroll
                for (int j = 0; j < 4; j++) {
                    accR[i][j] += ck[i] * h[j];
                    accI[i][j] += sk[i] * h[j];
                }
        }
    }

    const int kbase = kt * 32 + ty * 4;
    float* baseR = sfp + (size_t)sp * SFSZ;
    float* baseI = sfp + (size_t)(SFSPLIT + sp) * SFSZ;
#pragma unroll
    for (int i = 0; i < 4; i++) {
        int k = kbase + i;
        if (k < NK) {
            float4 kfv = make_float4(0.f, 0.f, 0.f, 0.f);
#pragma unroll
            for (int j = 0; j < 8; j++) {
                float kd = kdwn[k * 8 + j];
                float4 wv = ((const float4*)WupE)[(size_t)j * 32 + tx];
                kfv.x += kd * wv.x; kfv.y += kd * wv.y;
                kfv.z += kd * wv.z; kfv.w += kd * wv.w;
            }
            float vx = kfv.x * 0.01f, vy = kfv.y * 0.01f, vz = kfv.z * 0.01f, vw = kfv.w * 0.01f;
            size_t o = ((size_t)(b * NK + k)) * C + tx * 4;
            *(float4*)(baseR + o) = make_float4(accR[i][0] * vx, accR[i][1] * vy,
                                                accR[i][2] * vz, accR[i][3] * vw);
            *(float4*)(baseI + o) = make_float4(accI[i][0] * vx, accI[i][1] * vy,
                                                accI[i][2] * vz, accI[i][3] * vw);
        }
    }
}

// ---------------- reduce sfp partials -> bf16 transposed sfrT/sfiT [b][c][kpad] ----------------
__global__ __launch_bounds__(256) void k_sfredT(
    const float* __restrict__ sfp,
    unsigned short* __restrict__ sfrT, unsigned short* __restrict__ sfiT)
{
    const int kc = blockIdx.x * 16;
    const int b = blockIdx.y;
    __shared__ float Tr[16 * 128];
    __shared__ float Ti[16 * 128];
    const int tid = threadIdx.x;
    const size_t S4 = SFSZ / 4;
    const float4* P4 = (const float4*)sfp;

    for (int idx = tid; idx < 16 * 32; idx += 256) {
        int kk = idx >> 5, c4 = idx & 31;
        float4 ar = make_float4(0.f, 0.f, 0.f, 0.f), ai = ar;
        if (kc + kk < NK) {
            size_t off = ((size_t)(b * NK + kc + kk)) * 32 + c4;
#pragma unroll
            for (int sp = 0; sp < SFSPLIT; sp++) {
                float4 r = P4[(size_t)sp * S4 + off];
                ar.x += r.x; ar.y += r.y; ar.z += r.z; ar.w += r.w;
                float4 q = P4[(size_t)(SFSPLIT + sp) * S4 + off];
                ai.x += q.x; ai.y += q.y; ai.z += q.z; ai.w += q.w;
            }
        }
        ((float4*)Tr)[idx] = ar;
        ((float4*)Ti)[idx] = ai;
    }
    __syncthreads();
    const int c = tid & 127;
    const int sel = tid >> 7;
    const float* T = sel ? Ti : Tr;
    unsigned short* out = sel ? sfiT : sfrT;
    unsigned short tmp[16];
#pragma unroll
    for (int kk = 0; kk < 16; kk++) tmp[kk] = f2bf(T[kk * 128 + c]);
    short8* dst = (short8*)(out + ((size_t)(b * 128 + c)) * NKP + kc);
    dst[0] = *(short8*)(tmp);
    dst[1] = *(short8*)(tmp + 8);
}

// ---------------- fused he back-projection (MFMA) + he-MLP ----------------
__global__ __launch_bounds__(256) void k_he_mlp(
    const unsigned short* __restrict__ cosdb, const unsigned short* __restrict__ sindb,
    const unsigned short* __restrict__ sfrT, const unsigned short* __restrict__ sfiT,
    const int* __restrict__ gs,
    const unsigned short* __restrict__ Wm1t, const float* __restrict__ bm1,
    const unsigned short* __restrict__ Wm2t, const float* __restrict__ bm2,
    float* __restrict__ he2)
{
    constexpr int ASH = 136;
    constexpr int BSH = 72;
    __shared__ __align__(16) char smem[54272];
    unsigned short* Ca = (unsigned short*)smem;
    unsigned short* Sa = (unsigned short*)(smem + 8704);
    unsigned short* Br = (unsigned short*)(smem + 17408);
    unsigned short* Bi = (unsigned short*)(smem + 35840);
    unsigned short* Xs = (unsigned short*)smem;
    unsigned short* Ts = (unsigned short*)(smem + 8704);
    unsigned short* Ws = (unsigned short*)(smem + 17408);

    const int b = blockIdx.y;
    const int a0g = gs[b], a1g = gs[b + 1];
    const int a0 = a0g + blockIdx.x * 32;
    if (a0 >= a1g) return;
    const int nal = min(32, a1g - a0);
    const int tid = threadIdx.x;

    const short8 z8 = (short8){0,0,0,0,0,0,0,0};
    for (int idx = tid; idx < 32 * 16; idx += 256) {
        int r = idx >> 4, s = idx & 15;
        short8 cv = z8, sv = z8;
        if (r < nal) {
            cv = ((const short8*)cosdb)[(size_t)(a0 + r) * 16 + s];
            sv = ((const short8*)sindb)[(size_t)(a0 + r) * 16 + s];
        }
        *(short8*)(Ca + r * ASH + s * 8) = cv;
        *(short8*)(Sa + r * ASH + s * 8) = sv;
    }

    const int wave = tid >> 6;
    const int lane = tid & 63;
    const int q = lane >> 4;
    const int l16 = lane & 15;
    const int mh = (wave & 1) * 16;
    const int nh = (wave >> 1) * 64;

    f32x4 acc[4];
#pragma unroll
    for (int ni = 0; ni < 4; ni++) acc[ni] = (f32x4){0.f, 0.f, 0.f, 0.f};

#pragma unroll
    for (int kc2 = 0; kc2 < 2; kc2++) {
        __syncthreads();
        for (int idx = tid; idx < 128 * 8; idx += 256) {
            int c = idx >> 3, s = idx & 7;
            size_t gi = (size_t)(b * 128 + c) * 16 + kc2 * 8 + s;
            *(short8*)(Br + c * BSH + s * 8) = ((const short8*)sfrT)[gi];
            *(short8*)(Bi + c * BSH + s * 8) = ((const short8*)sfiT)[gi];
        }
        __syncthreads();
#pragma unroll
        for (int ks = 0; ks < 2; ks++) {
            short8 ar = *(const short8*)(Ca + (mh + l16) * ASH + kc2 * 64 + ks * 32 + q * 8);
            short8 ai = *(const short8*)(Sa + (mh + l16) * ASH + kc2 * 64 + ks * 32 + q * 8);
#pragma unroll
            for (int ni = 0; ni < 4; ni++) {
                short8 br = *(const short8*)(Br + (nh + ni * 16 + l16) * BSH + ks * 32 + q * 8);
                acc[ni] = __builtin_amdgcn_mfma_f32_16x16x32_bf16(ar, br, acc[ni], 0, 0, 0);
                short8 bi = *(const short8*)(Bi + (nh + ni * 16 + l16) * BSH + ks * 32 + q * 8);
                acc[ni] = __builtin_amdgcn_mfma_f32_16x16x32_bf16(ai, bi, acc[ni], 0, 0, 0);
            }
        }
    }
    __syncthreads();

#pragma unroll
    for (int ni = 0; ni < 4; ni++) {
#pragma unroll
        for (int r = 0; r < 4; r++)
            Xs[(mh + q * 4 + r) * ASH + nh + ni * 16 + l16] = f2bf(acc[ni][r]);
    }
    __syncthreads();
    for (int idx = tid; idx < 128 * 16; idx += 256) {
        int r = idx >> 4, s = idx & 15;
        *(short8*)(Ws + r * ASH + s * 8) = ((const short8*)Wm1t)[(size_t)r * 16 + s];
    }
    __syncthreads();

    f32x4 acc2[4];
#pragma unroll
    for (int ni = 0; ni < 4; ni++) acc2[ni] = (f32x4){0.f, 0.f, 0.f, 0.f};
#pragma unroll
    for (int kc = 0; kc < 4; kc++) {
        short8 a = *(const short8*)(Xs + (mh + l16) * ASH + kc * 32 + q * 8);
#pragma unroll
        for (int ni = 0; ni < 4; ni++) {
            short8 bb = *(const short8*)(Ws + (nh + ni * 16 + l16) * ASH + kc * 32 + q * 8);
            acc2[ni] = __builtin_amdgcn_mfma_f32_16x16x32_bf16(a, bb, acc2[ni], 0, 0, 0);
        }
    }
#pragma unroll
    for (int ni = 0; ni < 4; ni++) {
        float bv = bm1[nh + ni * 16 + l16];
#pragma unroll
        for (int r = 0; r < 4; r++)
            Ts[(mh + q * 4 + r) * ASH + nh + ni * 16 + l16] = f2bf(dsilu(acc2[ni][r] + bv));
    }
    __syncthreads();
    for (int idx = tid; idx < 128 * 16; idx += 256) {
        int r = idx >> 4, s = idx & 15;
        *(short8*)(Ws + r * ASH + s * 8) = ((const short8*)Wm2t)[(size_t)r * 16 + s];
    }
    __syncthreads();
#pragma unroll
    for (int ni = 0; ni < 4; ni++) acc2[ni] = (f32x4){0.f, 0.f, 0.f, 0.f};
#pragma unroll
    for (int kc = 0; kc < 4; kc++) {
        short8 a = *(const short8*)(Ts + (mh + l16) * ASH + kc * 32 + q * 8);
#pragma unroll
        for (int ni = 0; ni < 4; ni++) {
            short8 bb = *(const short8*)(Ws + (nh + ni * 16 + l16) * ASH + kc * 32 + q * 8);
            acc2[ni] = __builtin_amdgcn_mfma_f32_16x16x32_bf16(a, bb, acc2[ni], 0, 0, 0);
        }
    }
#pragma unroll
    for (int ni = 0; ni < 4; ni++) {
        int col = nh + ni * 16 + l16;
        float bv = bm2[col];
#pragma unroll
        for (int r = 0; r < 4; r++) {
            int lrow = mh + q * 4 + r;
            if (lrow < nal)
                he2[(size_t)(a0 + lrow) * C + col] = dsilu(acc2[ni][r] + bv);
        }
    }
}

// ---------------- fused gather (slot-ordered) + Wmix + residual + energy ----------------
__global__ __launch_bounds__(128) void k_gather_mix(
    const unsigned short* __restrict__ wbuf, const float* __restrict__ hu,
    const float* __restrict__ Y, const int* __restrict__ srcP,
    const int* __restrict__ offs,
    const float* __restrict__ w2, const float* __restrict__ w3,
    const float* __restrict__ Wmix, const float* __restrict__ h,
    const float* __restrict__ he2,
    const float* __restrict__ Wr0, const float* __restrict__ Wr1a,
    const float* __restrict__ Wr1b, int mode,
    float* __restrict__ hn, float* __restrict__ nebuf)
{
    int n = blockIdx.x, c = threadIdx.x;
    int j0 = offs[n], j1 = offs[n + 1];
    float A[16];
#pragma unroll
    for (int s = 0; s < 16; s++) A[s] = 0.f;
    for (int j = j0; j < j1; j++) {
        int s = srcP[j];
        float huc = hu[(size_t)s * C + c];
        ushort4 wv = *(const ushort4*)(wbuf + (size_t)j * 512 + c * 4);
        const float4* Yp = (const float4*)(Y + (size_t)j * 16);
        float4 y0 = Yp[0], y1 = Yp[1], y2 = Yp[2], y3 = Yp[3];
        float m0 = bf2f(wv.x) * huc, m1 = bf2f(wv.y) * huc;
        float m2 = bf2f(wv.z) * huc, m3 = bf2f(wv.w) * huc;
        A[0] += m0 * y0.x;
        A[1] += m1 * y0.y;  A[2]  += m1 * y0.z;  A[3]  += m1 * y0.w;
        A[4] += m2 * y1.x;  A[5]  += m2 * y1.y;  A[6]  += m2 * y1.z;  A[7] += m2 * y1.w;
        A[8] += m2 * y2.x;
        A[9] += m3 * y2.y;  A[10] += m3 * y2.z;  A[11] += m3 * y2.w;
        A[12] += m3 * y3.x; A[13] += m3 * y3.y;  A[14] += m3 * y3.z;  A[15] += m3 * y3.w;
    }
    const float inv = 1.0f / AVGN;
#pragma unroll
    for (int s = 0; s < 16; s++) A[s] *= inv;
    float scal = A[0];
    float i0 = A[0] * A[0];
    float i1 = A[1] * A[1] + A[2] * A[2] + A[3] * A[3];
    float i2 = A[4] * A[4] + A[5] * A[5] + A[6] * A[6] + A[7] * A[7] + A[8] * A[8];
    float i3 = A[9] * A[9] + A[10] * A[10] + A[11] * A[11] + A[12] * A[12] +
               A[13] * A[13] + A[14] * A[14] + A[15] * A[15];
    float t2 = i0 * w2[c] + i1 * w2[C + c] + i2 * w2[2 * C + c] + i3 * w2[3 * C + c];
    float t3 = i0 * w3[c] + i1 * w3[C + c] + i2 * w3[2 * C + c] + i3 * w3[3 * C + c];
    float fe_c = scal + t2 + scal * t3;

    __shared__ float fs[128];
    __shared__ float red[16];
    fs[c] = fe_c;
    __syncthreads();

    float mix = 0.f;
#pragma unroll 8
    for (int k = 0; k < 128; k++) mix += fs[k] * Wmix[(size_t)k * C + c];

    float hnv = SKIPF * (mix + h[(size_t)n * C + c] + he2[(size_t)n * C + c]);
    hn[(size_t)n * C + c] = hnv;

    __syncthreads();
    fs[c] = hnv;
    __syncthreads();

    if (mode == 0) {
        float v = hnv * Wr0[c];
#pragma unroll
        for (int o = 32; o; o >>= 1) v += __shfl_down(v, o, 64);
        if ((c & 63) == 0) red[c >> 6] = v;
        __syncthreads();
        if (c == 0) nebuf[n] = red[0] + red[1];
    } else {
        if (c < 16) {
            float s = 0.f;
#pragma unroll 8
            for (int cc = 0; cc < 128; cc++) s += fs[cc] * Wr1a[cc * 16 + c];
            red[c] = dsilu(s) * Wr1b[c];
        }
        __syncthreads();
        if (c == 0) {
            float s = 0.f;
#pragma unroll
            for (int j = 0; j < 16; j++) s += red[j];
            nebuf[n] = s;
        }
    }
}

// ---------------- final per-graph energy reduction ----------------
__global__ __launch_bounds__(256) void k_reduceE(
    const float* __restrict__ e0buf, const float* __restrict__ nebuf,
    const int* __restrict__ gs, float* __restrict__ Eout)
{
    int b = blockIdx.x, t = threadIdx.x;
    int n0 = gs[b], n1 = gs[b + 1];
    float s = 0.f;
    for (int n = n0 + t; n < n1; n += 256)
        s += e0buf[n] + nebuf[n] + nebuf[NA + n];
#pragma unroll
    for (int o = 32; o; o >>= 1) s += __shfl_down(s, o, 64);
    __shared__ float red[4];
    if ((t & 63) == 0) red[t >> 6] = s;
    __syncthreads();
    if (t == 0) Eout[b] = red[0] + red[1] + red[2] + red[3];
}

// ---------------- workspace layout (floats) ----------------
constexpr size_t NAC   = (size_t)NA * C;
constexpr size_t F_COSD = 0;
constexpr size_t F_SIND = F_COSD + (size_t)NA * NKP;
constexpr size_t F_Y    = F_SIND + (size_t)NA * NKP;
constexpr size_t F_EF   = F_Y + (size_t)NE * 16;
constexpr size_t F_H    = F_EF + (size_t)NE * 8;
constexpr size_t F_HN   = F_H + NAC;
constexpr size_t F_HRES = F_HN + NAC;
constexpr size_t F_T1   = F_HRES + NAC;
constexpr size_t F_HE2  = F_T1 + NAC;
constexpr size_t F_HU   = F_HE2 + NAC;
constexpr size_t F_TA   = F_HU + NAC;
constexpr size_t F_TB   = F_TA + (size_t)NE * 64;
constexpr size_t F_WTS  = F_TB + (size_t)NE * 64;
constexpr size_t F_W    = F_WTS + 128 * 1024;
constexpr size_t F_SFR  = F_W + (size_t)NE * 512;
constexpr size_t F_SFI  = F_SFR + SFSZ;
constexpr size_t F_SFP  = F_SFI + SFSZ;
constexpr size_t F_KD   = F_SFP + 2 * (size_t)SFSPLIT * SFSZ;
constexpr size_t F_E0   = F_KD + 1024;
constexpr size_t F_NE   = F_E0 + NA;
constexpr size_t F_CB   = F_NE + 2 * (size_t)NA;
constexpr size_t F_SB   = F_CB + (size_t)NA * 64;
constexpr size_t F_END  = F_SB + (size_t)NA * 64;
constexpr size_t I_BASE = ((F_END * 4 + 255) / 256) * 256;

extern "C" void kernel_launch(void* const* d_in, const int* in_sizes, int n_in,
                              void* d_out, int out_size, void* d_ws, size_t ws_size,
                              hipStream_t stream) {
    const float* pos    = (const float*)d_in[0];
    const float* na     = (const float*)d_in[1];
    const float* shifts = (const float*)d_in[2];
    const int*   eidx   = (const int*)d_in[3];
    const int*   batch  = (const int*)d_in[4];
    const float* kgrid  = (const float*)d_in[5];
    const float* krbf   = (const float*)d_in[6];
    const float* Wemb   = (const float*)d_in[7];
    const float* aE     = (const float*)d_in[8];
    const float* rW1    = (const float*)d_in[9];
    const float* rb1    = (const float*)d_in[10];
    const float* rW2    = (const float*)d_in[11];
    const float* rb2    = (const float*)d_in[12];
    const float* rW3    = (const float*)d_in[13];
    const float* rb3    = (const float*)d_in[14];
    const float* rW4    = (const float*)d_in[15];
    const float* Wup    = (const float*)d_in[16];
    const float* w2     = (const float*)d_in[17];
    const float* w3     = (const float*)d_in[18];
    const float* Wmix   = (const float*)d_in[19];
    const float* Wr0    = (const float*)d_in[20];
    const float* Wr1a   = (const float*)d_in[21];
    const float* Wr1b   = (const float*)d_in[22];
    const float* Wdown  = (const float*)d_in[23];
    const float* WupE   = (const float*)d_in[24];
    const float* Wpre1  = (const float*)d_in[25];
    const float* bpre1  = (const float*)d_in[26];
    const float* Wpre2  = (const float*)d_in[27];
    const float* bpre2  = (const float*)d_in[28];
    const float* Wm1    = (const float*)d_in[29];
    const float* bm1    = (const float*)d_in[30];
    const float* Wm2    = (const float*)d_in[31];
    const float* bm2    = (const float*)d_in[32];

    float* fw = (float*)d_ws;
    float* cosd = fw + F_COSD;
    float* sind = fw + F_SIND;
    float* Ybuf = fw + F_Y;
    float* h    = fw + F_H;
    float* hn   = fw + F_HN;
    float* hres = fw + F_HRES;
    float* he2  = fw + F_HE2;
    float* hu   = fw + F_HU;
    unsigned short* W4bt = (unsigned short*)(fw + F_WTS);
    unsigned short* W2bt  = W4bt + (size_t)2 * 512 * 64;
    unsigned short* W3bt  = W2bt + (size_t)2 * 64 * 64;
    unsigned short* Wm1bt = W3bt + (size_t)2 * 64 * 64;
    unsigned short* Wm2bt = Wm1bt + (size_t)2 * 128 * 128;
    unsigned short* Wp1bt = Wm2bt + (size_t)2 * 128 * 128;
    unsigned short* Wp2bt = Wp1bt + (size_t)2 * 128 * 128;
    unsigned short* Wupbt = Wp2bt + (size_t)2 * 128 * 128;
    unsigned short* W1bt  = Wupbt + (size_t)2 * 128 * 128;
    unsigned short* wbuf = (unsigned short*)(fw + F_W);
    unsigned short* sfrT = (unsigned short*)(fw + F_SFR);
    unsigned short* sfiT = (unsigned short*)(fw + F_SFI);
    float* sfp  = fw + F_SFP;
    float* kdwn = fw + F_KD;
    float* e0buf = fw + F_E0;
    float* nebuf = fw + F_NE;
    unsigned short* cosdb = (unsigned short*)(fw + F_CB);
    unsigned short* sindb = (unsigned short*)(fw + F_SB);

    int* ip     = (int*)((char*)d_ws + I_BASE);
    int* deg    = ip;
    int* offs   = ip + NA;
    int* cursor = ip + 2 * NA + 1;
    int* perm   = ip + 3 * NA + 1;
    int* srcP   = perm + NE;
    int* gs     = srcP + NE;

    float* Eout = (float*)d_out;

    hipMemsetAsync(deg, 0, NA * sizeof(int), stream);

    k_setup<<<TKEND, 128, 0, stream>>>(
        na, Wemb, aE, batch, pos, kgrid, krbf, Wdown,
        rW4, rW2, rW3, rW1, Wm1, Wm2, Wpre1, Wpre2, Wup, eidx,
        h, e0buf, cosd, sind, cosdb, sindb, kdwn,
        W4bt, W2bt, W3bt, W1bt, Wm1bt, Wm2bt, Wp1bt, Wp2bt, Wupbt, gs, deg);
    k_scan<<<1, 1024, 0, stream>>>(deg, offs, cursor);
    k_fill<<<NE / 256, 256, 0, stream>>>(eidx, cursor, perm, srcP);

    // ---- edge branch: one fused kernel (geometry inline), both layers, MT=64 ----
    k_edge_mlp<<<2 * NE / 64, 256, 0, stream>>>(pos, shifts, eidx, perm,
                                                W1bt, rb1, W2bt, rb2,
                                                W3bt, rb3, W4bt, wbuf, Ybuf);

    const dim3 gSF(BG, 4, SFSPLIT);
    const dim3 gRT(8, BG);
    const dim3 gHE(16, BG);

    for (int i = 0; i < 2; i++) {
        const float* bpre1_i = bpre1 + (size_t)i * C;
        const float* bpre2_i = bpre2 + (size_t)i * C;
        const float* WupE_i  = WupE + (size_t)i * 8 * C;
        const float* bm1_i   = bm1 + (size_t)i * C;
        const float* bm2_i   = bm2 + (size_t)i * C;
        const float* w2_i    = w2 + (size_t)i * 4 * C;
        const float* w3_i    = w3 + (size_t)i * 4 * C;
        const float* Wmix_i  = Wmix + (size_t)i * C * C;
        const unsigned short* Wm1bt_i = Wm1bt + (size_t)i * 128 * 128;
        const unsigned short* Wm2bt_i = Wm2bt + (size_t)i * 128 * 128;
        const unsigned short* Wp1bt_i = Wp1bt + (size_t)i * 128 * 128;
        const unsigned short* Wp2bt_i = Wp2bt + (size_t)i * 128 * 128;
        const unsigned short* Wupbt_i = Wupbt + (size_t)i * 128 * 128;
        const unsigned short* wbuf_i = wbuf + (size_t)i * NE * 512;

        // fused pre-MLP + Wup
        k_pre<<<NA / 32, 256, 0, stream>>>(h, Wp1bt_i, bpre1_i, Wupbt_i,
                                           Wp2bt_i, bpre2_i, hu, hres);

        // Ewald branch: sf -> sfredT -> fused MFMA (he + he-MLP)
        k_sf<<<gSF, 256, 0, stream>>>(hres, cosd, sind, gs, kdwn, WupE_i, sfp);
        k_sfredT<<<gRT, 256, 0, stream>>>(sfp, sfrT, sfiT);
        k_he_mlp<<<gHE, 256, 0, stream>>>(cosdb, sindb, sfrT, sfiT, gs,
                                          Wm1bt_i, bm1_i, Wm2bt_i, bm2_i, he2);

        // fused gather (sequential) + Wmix + residual + energy
        k_gather_mix<<<NA, 128, 0, stream>>>(wbuf_i, hu, Ybuf, srcP, offs,
                                             w2_i, w3_i, Wmix_i, h, he2,
                                             Wr0, Wr1a, Wr1b, (i == 0) ? 0 : 1,
                                             hn, nebuf + (size_t)i * NA);

        float* tmp = h; h = hn; hn = tmp;
    }

    k_reduceE<<<BG, 256, 0, stream>>>(e0buf, nebuf, gs, Eout);
}